// Round 8
// baseline (173.797 us; speedup 1.0000x reference)
//
#include <hip/hip_runtime.h>
#include <math.h>

// RC thermal model: x' = A x + b0*To(t) + Bq, RK4 h=30, T=1e6 steps.
// Per step: x_{t+1} = M x_t + c + al*To[t] + be*To[t+1].
// R16: CH 8->4 (977 blocks) at __launch_bounds__(256,4): R14 counters
// showed fused at 17% occupancy / 25% VALU with resource slack (VGPR 92,
// LDS 16K) -- issue-starved at 7.6 waves/CU because the CH=8 grid is only
// 489 blocks. CH=4 doubles waves/CU to 15.3 (R9 proved the extra scan
// work is free in this latency-bound regime). Math is verbatim the
// verified R0 CH=4 kernel (6-col K, M^(4*2^l) levels, 64-slot lookback
// = same 65536-step truncation, 16 Pd, 4-step expand) in the proven
// fused structure (publish/spin + LDS-mirrored constants, 23.1KB/block;
// 4 blocks/CU = 92KB < 160). Deadlock-safe: capacity 4/CU guaranteed
// (VGPR<=128 by bounds, LDS<40K, 16<32 waves) -> 1024 >= 977 co-resident.
// Setup: CH=4 table with parallel Pd products (2 barriered + 3 free
// batches replace R0's 14-round serial Pd chain).
// Structure: setup (plain) + fused_scan (plain). CH=4, BLK=256, NB=977.

#define S_STEPS 999999
#define CH      4
#define BLK     256
#define NB      977          // 977*256*4 = 1,000,448 >= S_STEPS
#define NCHUNK  250000       // active chunks (last partial: 3 steps)
#define LASTFULL 249998      // g <= LASTFULL: To[4g+4] in bounds

// ws float offsets (16B-aligned) -- R0 layout
#define OFF_M   0            // 144: M
#define OFF_C   144          // 12
#define OFF_AL  156          // 12
#define OFF_BE  168          // 12
#define OFF_K   192          // 72: K cols [col][12], col0 = const (6 cols)
#define OFF_P2  264          // 8*144: [l]=M^(4*2^l) l=0..5 (M^4..M^128),
                             //        [6]=M^256, [7]=M^512
#define OFF_PA  1416         // 2*144: PA[0] unused, PA[1]=M^768
#define OFF_PL  1704         // 3*144: M^1024, M^2048, M^3072
#define OFF_PD  2136         // 16*144: Pd[i]=M^(4096i), i=0..15 (Pd[0]=I)
#define NCONS   4440         // floats mirrored to LDS
#define OFF_AGG 4440         // 977*12 block aggregates (end 16164)
#define OFF_FLAG 16164       // 977 int flags

#define FMA4(Q,a,b,c,d,acc) fmaf((Q).w,(d),fmaf((Q).z,(c),fmaf((Q).y,(b),fmaf((Q).x,(a),(acc)))))

// y += P(12x12 row-major, 16B-aligned) * x
__device__ __forceinline__ void mv_acc(const float* Pf, const float* x, float* y) {
  const float4* P = reinterpret_cast<const float4*>(Pf);
#pragma unroll
  for (int i = 0; i < 12; ++i) {
    float4 a = P[3*i], b = P[3*i+1], c = P[3*i+2];
    y[i] = FMA4(c, x[8],x[9],x[10],x[11],
            FMA4(b, x[4],x[5],x[6],x[7],
             FMA4(a, x[0],x[1],x[2],x[3], y[i])));
  }
}

// dot(P row (16B-aligned), xv[0..11] scalars)
__device__ __forceinline__ float rowdot(const float* Prow, const float* xv) {
  const float4* P = reinterpret_cast<const float4*>(Prow);
  float4 a = P[0], b = P[1], c = P[2];
  return FMA4(c, xv[8],xv[9],xv[10],xv[11],
          FMA4(b, xv[4],xv[5],xv[6],xv[7],
           FMA4(a, xv[0],xv[1],xv[2],xv[3], 0.f)));
}

// v = K[:,0] + sum_{s=0..4} K[:,s+1]*tos[s]  (CH=4: 6 cols)
__device__ __forceinline__ void fold_chunk(const float* cons,
                                           const float* tos, float* v) {
  const float4* Kq = reinterpret_cast<const float4*>(cons + OFF_K);
  float4 c0=Kq[0], c1=Kq[1], c2=Kq[2];
  v[0]=c0.x; v[1]=c0.y; v[2]=c0.z; v[3]=c0.w;
  v[4]=c1.x; v[5]=c1.y; v[6]=c1.z; v[7]=c1.w;
  v[8]=c2.x; v[9]=c2.y; v[10]=c2.z; v[11]=c2.w;
#pragma unroll
  for (int s = 0; s < 5; ++s) {
    float ts = tos[s];
    float4 ka=Kq[3*(s+1)], kb=Kq[3*(s+1)+1], kc=Kq[3*(s+1)+2];
    v[0]=fmaf(ka.x,ts,v[0]); v[1]=fmaf(ka.y,ts,v[1]); v[2]=fmaf(ka.z,ts,v[2]); v[3]=fmaf(ka.w,ts,v[3]);
    v[4]=fmaf(kb.x,ts,v[4]); v[5]=fmaf(kb.y,ts,v[5]); v[6]=fmaf(kb.z,ts,v[6]); v[7]=fmaf(kb.w,ts,v[7]);
    v[8]=fmaf(kc.x,ts,v[8]); v[9]=fmaf(kc.y,ts,v[9]); v[10]=fmaf(kc.z,ts,v[10]); v[11]=fmaf(kc.w,ts,v[11]);
  }
}

__global__ void __launch_bounds__(512) setup_kernel(
    const float* __restrict__ t_eval, const float* __restrict__ A,
    const float* __restrict__ Bm, const float* __restrict__ loads_raw,
    const float* __restrict__ areas, float* ws) {
  __shared__ double H1[144], H2[144], H3[144], H4[144], Md[144];
  __shared__ double Qa[144], Qb[144];
  __shared__ double C256s[144], C512s[144], C1024s[144], C2048s[144];
  __shared__ double Pd1s[144], Pd2s[144], Pd4s[144], Pd8s[144];
  __shared__ double Pd3s[144], Pd5s[144], Pd6s[144], Pd7s[144];
  __shared__ double cd[12], ald[12], bed[12], b0d[12], bqd[12];
  __shared__ double Vv[3][12], Kd[72];
  int t = threadIdx.x;
  for (int f = t; f < NB; f += 512)            // reset lookback flags
    ((int*)(ws + OFF_FLAG))[f] = 0;
  double h = (double)t_eval[1] - (double)t_eval[0];
  if (t < 144) H1[t] = h * (double)A[t];
  if (t < 12) {
    b0d[t] = (double)Bm[t*11];
    double s = 0.0;
    for (int r = 0; r < 10; ++r) {
      double gq = 50.0 / (1.0 + exp(-(double)loads_raw[10 + r]));
      s += (double)Bm[t*11 + 1 + r] * (gq * (double)areas[r]);
    }
    bqd[t] = s;
  }
  if (t < 72) Kd[t] = 0.0;
  __syncthreads();
  if (t < 144) {                              // H2 = H1*H1
    int i=t/12, j=t%12; double s=0.0;
#pragma unroll
    for (int m = 0; m < 12; ++m) s += H1[i*12+m]*H1[m*12+j];
    H2[t]=s;
  }
  __syncthreads();
  if (t < 288) {                              // H3 = H2*H1 | H4 = H2*H2
    int w=t/144, e=t%144, i=e/12, j=e%12;
    const double* Bp = w ? H2 : H1;
    double s = 0.0;
#pragma unroll
    for (int m = 0; m < 12; ++m) s += H2[i*12+m]*Bp[m*12+j];
    (w ? H4 : H3)[e] = s;
  }
  __syncthreads();
  if (t < 12) {
    double hb=0,h2b=0,h3b=0,hb0=0,h2b0=0,h3b0=0;
#pragma unroll
    for (int m = 0; m < 12; ++m) {
      hb  += H1[t*12+m]*bqd[m]; h2b  += H2[t*12+m]*bqd[m]; h3b  += H3[t*12+m]*bqd[m];
      hb0 += H1[t*12+m]*b0d[m]; h2b0 += H2[t*12+m]*b0d[m]; h3b0 += H3[t*12+m]*b0d[m];
    }
    double h6 = h / 6.0;
    cd[t]  = h6*(6.0*bqd[t] + 3.0*hb + h2b + 0.25*h3b);
    ald[t] = h6*(3.0*b0d[t] + 2.0*hb0 + 0.75*h2b0 + 0.25*h3b0);
    bed[t] = h6*(3.0*b0d[t] + hb0 + 0.25*h2b0);
    Vv[0][t]=ald[t]; Vv[1][t]=bed[t]; Vv[2][t]=cd[t];
    // r=0 K contributions (CH=4): col4 += al, col5 += be, col0 += c
    Kd[48+t] += ald[t]; Kd[60+t] += bed[t]; Kd[t] += cd[t];
  }
  if (t >= 144 && t < 288) {
    int e=t-144, i=e/12, j=e%12;
    Md[e] = (i==j ? 1.0 : 0.0) + H1[e] + 0.5*H2[e] + H3[e]/6.0 + H4[e]/24.0;
  }
  __syncthreads();
  if (t < 144) { ws[OFF_M+t] = (float)Md[t]; Qa[t] = Md[t]; }
  if (t < 12) {
    ws[OFF_C+t]=(float)cd[t]; ws[OFF_AL+t]=(float)ald[t]; ws[OFF_BE+t]=(float)bed[t];
  }
  __syncthreads();
  // chain r=1..15: src=M^(2^(r-1)) -> dst=M^(2^r). Overlapped K rounds
  // r=1..3 (threads 256..291): Vv=M^r*{al,be,c}; Kd cols (4-r),(5-r),0.
  double* src = Qa; double* dst = Qb;
  for (int r = 1; r <= 15; ++r) {
    double acc = 0.0, ks = 0.0;
    if (t < 144) {
      int i=t/12, j=t%12;
#pragma unroll
      for (int m = 0; m < 12; ++m) acc += src[i*12+m]*src[m*12+j];
    }
    int w=0, i2=0;
    if (r <= 3 && t >= 256 && t < 292) {
      w=(t-256)/12; i2=(t-256)%12;
#pragma unroll
      for (int m = 0; m < 12; ++m) ks += Md[i2*12+m]*Vv[w][m];
    }
    __syncthreads();
    if (t < 144) {
      dst[t] = acc;
      if (r >= 2 && r <= 9) ws[OFF_P2+(r-2)*144+t] = (float)acc;  // M^4..M^512
      if (r == 8)  C256s[t]=acc;
      if (r == 9)  C512s[t]=acc;
      if (r == 10) { C1024s[t]=acc; ws[OFF_PL+t]        = (float)acc; }
      if (r == 11) { C2048s[t]=acc; ws[OFF_PL+144+t]    = (float)acc; }
      if (r == 12) { Pd1s[t]=acc;   ws[OFF_PD+144+t]    = (float)acc; }  // M^4096
      if (r == 13) { Pd2s[t]=acc;   ws[OFF_PD+2*144+t]  = (float)acc; }  // M^8192
      if (r == 14) { Pd4s[t]=acc;   ws[OFF_PD+4*144+t]  = (float)acc; }  // M^16384
      if (r == 15) { Pd8s[t]=acc;   ws[OFF_PD+8*144+t]  = (float)acc; }  // M^32768
    }
    if (r <= 3 && t >= 256 && t < 292) {
      Vv[w][i2] = ks;
      if (w == 0) Kd[(4-r)*12+i2] += ks;
      else if (w == 1) Kd[(5-r)*12+i2] += ks;
      else Kd[i2] += ks;
    }
    __syncthreads();
    double* tmp = src; src = dst; dst = tmp;    // src = M^(2^r)
  }
  if (t < 72) ws[OFF_K+t] = (float)Kd[t];
  if (t < 144) ws[OFF_PD+t] = (t % 13 == 0) ? 1.f : 0.f;   // Pd[0]=I
  // product round A: M^768=C256*C512 ; M^3072=C1024*C2048 ; Pd3=Pd1*Pd2
  if (t < 432) {
    int w=t/144, e=t%144, i=e/12, j=e%12;
    const double* Ap = (w==0) ? C256s : ((w==1) ? C1024s : Pd1s);
    const double* Bp = (w==0) ? C512s : ((w==1) ? C2048s : Pd2s);
    double s = 0.0;
#pragma unroll
    for (int m = 0; m < 12; ++m) s += Ap[i*12+m]*Bp[m*12+j];
    if (w==0) ws[OFF_PA+144+e] = (float)s;
    else if (w==1) ws[OFF_PL+2*144+e] = (float)s;
    else { ws[OFF_PD+3*144+e] = (float)s; Pd3s[e] = s; }
  }
  __syncthreads();
  // product round B: Pd5=Pd1*Pd4 ; Pd6=Pd2*Pd4 ; Pd7=Pd3*Pd4
  if (t < 432) {
    int w=t/144, e=t%144, i=e/12, j=e%12;
    const double* Ap = (w==0) ? Pd1s : ((w==1) ? Pd2s : Pd3s);
    double s = 0.0;
#pragma unroll
    for (int m = 0; m < 12; ++m) s += Ap[i*12+m]*Pd4s[m*12+j];
    ws[OFF_PD+(5+w)*144+e] = (float)s;
    (w==0 ? Pd5s : (w==1 ? Pd6s : Pd7s))[e] = s;
  }
  __syncthreads();
  // barrier-free batches: Pd9..Pd15 = {Pd1,Pd2,Pd3,Pd4,Pd5,Pd6,Pd7}*Pd8
  if (t < 432) {
    int w=t/144, e=t%144, i=e/12, j=e%12;
    const double* Ap = (w==0) ? Pd1s : ((w==1) ? Pd2s : Pd3s);
    double s = 0.0;
#pragma unroll
    for (int m = 0; m < 12; ++m) s += Ap[i*12+m]*Pd8s[m*12+j];
    ws[OFF_PD+(9+w)*144+e] = (float)s;
  }
  if (t < 432) {
    int w=t/144, e=t%144, i=e/12, j=e%12;
    const double* Ap = (w==0) ? Pd4s : ((w==1) ? Pd5s : Pd6s);
    double s = 0.0;
#pragma unroll
    for (int m = 0; m < 12; ++m) s += Ap[i*12+m]*Pd8s[m*12+j];
    ws[OFF_PD+(12+w)*144+e] = (float)s;
  }
  if (t < 144) {
    int i=t/12, j=t%12;
    double s = 0.0;
#pragma unroll
    for (int m = 0; m < 12; ++m) s += Pd7s[i*12+m]*Pd8s[m*12+j];
    ws[OFF_PD+15*144+t] = (float)s;
  }
}

// Fused: LDS-mirror cons; fold+scan ONCE; agg tree; publish (release
// flag); spin on 64 predecessor flags; 64-slot lookback + merged prefix
// + 4-step expand. Plain launch, graph-capturable.
__global__ void __launch_bounds__(BLK, 4) fused_scan(
    const float* __restrict__ cons, const float* __restrict__ To,
    const float* __restrict__ x0, float* __restrict__ agg,
    int* __restrict__ flags, float* __restrict__ out) {
  __shared__ __align__(16) float Lc[NCONS];   // LDS mirror of cons
  __shared__ __align__(16) float Tw[48];      // wave totals
  __shared__ __align__(16) float Ta[24];      // agg tree level 1
  __shared__ __align__(16) float Pw[48];      // wave exclusive prefixes
  __shared__ __align__(16) float lkb[64*12];  // lookback stage-1 partials
  __shared__ __align__(16) float yv[16*12];
  __shared__ __align__(16) float zv[16*12];
  __shared__ __align__(16) float Xs[12];
  __shared__ __align__(16) float Qw[48];      // M^(256w)*Xs + Pw
  int k = threadIdx.x, b = blockIdx.x;
  int g = b*BLK + k, base = g*CH;
  bool active = (g < NCHUNK), fullc = (g <= LASTFULL);
  float to_[5];
#pragma unroll
  for (int i = 0; i < 5; ++i) to_[i] = 0.f;
  if (active) {
    const float4* tp = reinterpret_cast<const float4*>(To + base);
    float4 ta = tp[0];
    to_[0]=ta.x; to_[1]=ta.y; to_[2]=ta.z; to_[3]=ta.w;
    to_[4] = fullc ? To[base+4] : 0.f;
  }
  {                                  // mirror cons -> LDS (1110 float4)
    const float4* s4 = reinterpret_cast<const float4*>(cons);
    float4* d4 = reinterpret_cast<float4*>(Lc);
#pragma unroll
    for (int r = 0; r < 5; ++r) {
      int idx = k + r*BLK;
      if (idx < NCONS/4) d4[idx] = s4[idx];
    }
  }
  __syncthreads();
  const float* lc = Lc;              // all constant reads now LDS
  float v[12];
  if (fullc) fold_chunk(lc, to_, v);
  else {
#pragma unroll
    for (int i = 0; i < 12; ++i) v[i] = 0.f;
  }
  if (g == 0) {                      // fold x0 into chunk 0: v += M^4 x0
    float xi[12];
#pragma unroll
    for (int i = 0; i < 12; ++i) xi[i] = x0[i];
    mv_acc(lc + OFF_P2, xi, v);
  }
  int j = k & 63, w = k >> 6;
#pragma unroll
  for (int l = 0; l < 6; ++l) {      // in-wave inclusive scan
    int off = 1 << l;
    float nb[12];
#pragma unroll
    for (int i = 0; i < 12; ++i) nb[i] = __shfl_up(v[i], (unsigned)off, 64);
    if (j >= off) mv_acc(lc + OFF_P2 + l*144, nb, v);
  }
  float se[12];                      // exclusive in-wave scan
#pragma unroll
  for (int i = 0; i < 12; ++i) {
    float u = __shfl_up(v[i], 1u, 64);
    se[i] = (j == 0) ? 0.f : u;
  }
  if (j == 63) {
#pragma unroll
    for (int i = 0; i < 12; ++i) Tw[w*12 + i] = v[i];
  }
  __syncthreads();
  if (k < 24) {                      // (T0,T1),(T2,T3): M^256*left + right
    int p = k/12, comp = k - p*12;
    Ta[k] = rowdot(lc + OFF_P2 + 6*144 + comp*12, Tw + 2*p*12)
          + Tw[(2*p+1)*12 + comp];
  }
  __syncthreads();
  if (k < 12) {                      // agg[b] = M^512*Ta0 + Ta1 (agent)
    float val = rowdot(lc + OFF_P2 + 7*144 + k*12, Ta) + Ta[12 + k];
    __hip_atomic_store(&agg[b*12 + k], val, __ATOMIC_RELAXED,
                       __HIP_MEMORY_SCOPE_AGENT);
  }
  __syncthreads();
  if (k == 0)                        // publish: release flag
    __hip_atomic_store(&flags[b], 1, __ATOMIC_RELEASE,
                       __HIP_MEMORY_SCOPE_AGENT);
  // spin on 64 predecessors (threads k<64, one flag each)
  if (k < 64) {
    int src = b - 1 - k;
    if (src >= 0) {
      while (__hip_atomic_load(&flags[src], __ATOMIC_ACQUIRE,
                               __HIP_MEMORY_SCOPE_AGENT) == 0) {
        __builtin_amdgcn_s_sleep(1);
      }
    }
  }
  __syncthreads();
  // lookback stage 1: slot=4i+jj: lkb[slot] = M^(1024*jj)*agg[b-1-slot]
#pragma unroll
  for (int r = 0; r < 3; ++r) {
    int idx = k + r*BLK;             // 768 = 3*BLK exactly
    int slot = idx / 12, comp = idx - slot*12;
    int src = b - 1 - slot;
    float acc = 0.f;
    if (src >= 0) {
      int jj = slot & 3;
      const float* ag = agg + src*12;
      acc = (jj == 0) ? ag[comp]
          : rowdot(lc + OFF_PL + (jj-1)*144 + comp*12, ag);
    }
    lkb[idx] = acc;
  }
  __syncthreads();
  // yv[i] = sum_jj lkb[4i+jj]  (k<192)  |  Pw: P0=0, P1=T0  (k in [192,216))
  if (k < 192) {
    int i = k/12, comp = k - i*12;
    yv[k] = lkb[(4*i)*12+comp] + lkb[(4*i+1)*12+comp]
          + lkb[(4*i+2)*12+comp] + lkb[(4*i+3)*12+comp];
  } else if (k < 216) {
    int q = k - 192;                 // 0..23
    if (q < 12) Pw[q] = 0.f;         // P0
    else Pw[q] = Tw[q-12];           // P1 = T0
  }
  __syncthreads();
  // zv[i] = M^(4096i)*yv[i] (k<192) | P2 = M^256*P1 + T1 (k in [192,204))
  if (k < 192) {
    int i = k/12, comp = k - i*12;
    zv[k] = (i == 0) ? yv[comp]
          : rowdot(lc + OFF_PD + i*144 + comp*12, yv + i*12);
  } else if (k >= 192 && k < 204) {
    int comp = k - 192;
    Pw[24+comp] = rowdot(lc + OFF_P2 + 6*144 + comp*12, Pw+12) + Tw[12+comp];
  }
  __syncthreads();
  // Xs = sum_i zv[i] (k<12) | P3 = M^256*P2 + T2 (k in [192,204))
  if (k < 12) {
    float s = 0.f;
#pragma unroll
    for (int i = 0; i < 16; ++i) s += zv[i*12 + k];
    Xs[k] = s;
  } else if (k >= 192 && k < 204) {
    int comp = k - 192;
    Pw[36+comp] = rowdot(lc + OFF_P2 + 6*144 + comp*12, Pw+24) + Tw[24+comp];
  }
  __syncthreads();
  // Qw[w] = M^(256w)*Xs + Pw[w]  (w=0..3; matrices I, M^256, M^512, M^768)
  if (k < 48) {
    int ww = k/12, comp = k - ww*12;
    float acc;
    if (ww == 0) acc = Xs[comp];
    else if (ww == 1) acc = rowdot(lc + OFF_P2 + 6*144 + comp*12, Xs);
    else if (ww == 2) acc = rowdot(lc + OFF_P2 + 7*144 + comp*12, Xs);
    else acc = rowdot(lc + OFF_PA + 144 + comp*12, Xs);
    Qw[k] = acc + Pw[k];
  }
  __syncthreads();
  if (!active) return;               // all barriers done
  // per-thread: x = M^(4j)*Qw[w] + se   (bits of j, P2[0..5])
  float x[12];
#pragma unroll
  for (int i = 0; i < 12; ++i) x[i] = Qw[w*12 + i];
#pragma unroll
  for (int l = 0; l < 6; ++l) {
    if ((j >> l) & 1) {
      float vn[12];
#pragma unroll
      for (int i = 0; i < 12; ++i) vn[i] = 0.f;
      mv_acc(lc + OFF_P2 + l*144, x, vn);
#pragma unroll
      for (int i = 0; i < 12; ++i) x[i] = vn[i];
    }
  }
#pragma unroll
  for (int i = 0; i < 12; ++i) x[i] += se[i];
  if (b == 0 && k == 0) {
#pragma unroll
    for (int i = 0; i < 12; ++i) x[i] += x0[i];      // start state = x0
#pragma unroll
    for (int i = 0; i < 12; ++i) out[i] = x0[i];     // row 0
  }
  // expand: 4 unconditional steps, predicated stores (NO break).
  float cv[12], av[12], bv[12];
#pragma unroll
  for (int i = 0; i < 12; ++i) {
    cv[i] = lc[OFF_C + i]; av[i] = lc[OFF_AL + i]; bv[i] = lc[OFF_BE + i];
  }
  const float4* Mq = reinterpret_cast<const float4*>(lc + OFF_M);
#pragma unroll
  for (int s = 0; s < CH; ++s) {
    float tot = to_[s], ton = (s < CH-1) ? to_[s+1] : to_[4];
    float xn[12];
#pragma unroll
    for (int i = 0; i < 12; ++i) {
      float4 a = Mq[3*i], bq = Mq[3*i+1], c = Mq[3*i+2];
      xn[i] = FMA4(c, x[8],x[9],x[10],x[11],
               FMA4(bq, x[4],x[5],x[6],x[7],
                FMA4(a, x[0],x[1],x[2],x[3],
                 fmaf(bv[i],ton,fmaf(av[i],tot,cv[i])))));
    }
    int tt = base + s;
    if (tt < S_STEPS) {
      float4* op = reinterpret_cast<float4*>(out + (size_t)(tt+1)*12);
      op[0] = make_float4(xn[0],xn[1],xn[2],xn[3]);
      op[1] = make_float4(xn[4],xn[5],xn[6],xn[7]);
      op[2] = make_float4(xn[8],xn[9],xn[10],xn[11]);
    }
#pragma unroll
    for (int i = 0; i < 12; ++i) x[i] = xn[i];
  }
}

extern "C" void kernel_launch(void* const* d_in, const int* in_sizes, int n_in,
                              void* d_out, int out_size, void* d_ws, size_t ws_size,
                              hipStream_t stream) {
  const float* t_eval    = (const float*)d_in[0];
  const float* x0        = (const float*)d_in[1];
  const float* A         = (const float*)d_in[2];
  const float* B         = (const float*)d_in[3];
  const float* To        = (const float*)d_in[4];
  const float* loads_raw = (const float*)d_in[5];
  const float* areas     = (const float*)d_in[6];
  float* out = (float*)d_out;
  float* ws  = (float*)d_ws;

  setup_kernel<<<1, 512, 0, stream>>>(t_eval, A, B, loads_raw, areas, ws);
  fused_scan<<<NB, BLK, 0, stream>>>(ws, To, x0, ws + OFF_AGG,
                                     (int*)(ws + OFF_FLAG), out);
}

// Round 9
// 157.675 us; speedup vs baseline: 1.1022x; 1.1022x over previous
//
#include <hip/hip_runtime.h>
#include <math.h>

// RC thermal model: x' = A x + b0*To(t) + Bq, RK4 h=30, T=1e6 steps.
// Per step: x_{t+1} = M x_t + c + al*To[t] + be*To[t+1].
// R17: R16 (CH=4, 977 blocks, 4 blocks/CU -- occupancy 35% worked) with
// FENCE-FREE sync. R16's failure was cache maintenance, not occupancy:
// 977 release-wbl2s flushed partially-written out lines (WRITE 66->133MB
// doubled; FETCH 2.5->38.7MB = RMW refetch), per-poll acquire-invs nuked
// L2. Fix: relaxed agent atomics everywhere (sc1, LLC-direct on gfx950):
// agg stores relaxed; release = vmcnt drain + RELAXED flag store (no
// wbl2); spin = RELAXED polls (no inv); lookback reads agg via relaxed
// atomic scalar loads (no fence). Flag zeroing safe via setup's
// end-of-kernel flush. Math verbatim R16 (verified, absmax 4.0).
// Structure: setup (plain) + fused_scan (plain). CH=4, BLK=256, NB=977.

#define S_STEPS 999999
#define CH      4
#define BLK     256
#define NB      977          // 977*256*4 = 1,000,448 >= S_STEPS
#define NCHUNK  250000       // active chunks (last partial: 3 steps)
#define LASTFULL 249998      // g <= LASTFULL: To[4g+4] in bounds

// ws float offsets (16B-aligned)
#define OFF_M   0            // 144: M
#define OFF_C   144          // 12
#define OFF_AL  156          // 12
#define OFF_BE  168          // 12
#define OFF_K   192          // 72: K cols [col][12], col0 = const (6 cols)
#define OFF_P2  264          // 8*144: [l]=M^(4*2^l) l=0..5 (M^4..M^128),
                             //        [6]=M^256, [7]=M^512
#define OFF_PA  1416         // 2*144: PA[0] unused, PA[1]=M^768
#define OFF_PL  1704         // 3*144: M^1024, M^2048, M^3072
#define OFF_PD  2136         // 16*144: Pd[i]=M^(4096i), i=0..15 (Pd[0]=I)
#define NCONS   4440         // floats mirrored to LDS
#define OFF_AGG 4440         // 977*12 block aggregates (end 16164)
#define OFF_FLAG 16164       // 977 int flags

#define FMA4(Q,a,b,c,d,acc) fmaf((Q).w,(d),fmaf((Q).z,(c),fmaf((Q).y,(b),fmaf((Q).x,(a),(acc)))))

// y += P(12x12 row-major, 16B-aligned) * x
__device__ __forceinline__ void mv_acc(const float* Pf, const float* x, float* y) {
  const float4* P = reinterpret_cast<const float4*>(Pf);
#pragma unroll
  for (int i = 0; i < 12; ++i) {
    float4 a = P[3*i], b = P[3*i+1], c = P[3*i+2];
    y[i] = FMA4(c, x[8],x[9],x[10],x[11],
            FMA4(b, x[4],x[5],x[6],x[7],
             FMA4(a, x[0],x[1],x[2],x[3], y[i])));
  }
}

// dot(P row (16B-aligned), xv[0..11] scalars)
__device__ __forceinline__ float rowdot(const float* Prow, const float* xv) {
  const float4* P = reinterpret_cast<const float4*>(Prow);
  float4 a = P[0], b = P[1], c = P[2];
  return FMA4(c, xv[8],xv[9],xv[10],xv[11],
          FMA4(b, xv[4],xv[5],xv[6],xv[7],
           FMA4(a, xv[0],xv[1],xv[2],xv[3], 0.f)));
}

// v = K[:,0] + sum_{s=0..4} K[:,s+1]*tos[s]  (CH=4: 6 cols)
__device__ __forceinline__ void fold_chunk(const float* cons,
                                           const float* tos, float* v) {
  const float4* Kq = reinterpret_cast<const float4*>(cons + OFF_K);
  float4 c0=Kq[0], c1=Kq[1], c2=Kq[2];
  v[0]=c0.x; v[1]=c0.y; v[2]=c0.z; v[3]=c0.w;
  v[4]=c1.x; v[5]=c1.y; v[6]=c1.z; v[7]=c1.w;
  v[8]=c2.x; v[9]=c2.y; v[10]=c2.z; v[11]=c2.w;
#pragma unroll
  for (int s = 0; s < 5; ++s) {
    float ts = tos[s];
    float4 ka=Kq[3*(s+1)], kb=Kq[3*(s+1)+1], kc=Kq[3*(s+1)+2];
    v[0]=fmaf(ka.x,ts,v[0]); v[1]=fmaf(ka.y,ts,v[1]); v[2]=fmaf(ka.z,ts,v[2]); v[3]=fmaf(ka.w,ts,v[3]);
    v[4]=fmaf(kb.x,ts,v[4]); v[5]=fmaf(kb.y,ts,v[5]); v[6]=fmaf(kb.z,ts,v[6]); v[7]=fmaf(kb.w,ts,v[7]);
    v[8]=fmaf(kc.x,ts,v[8]); v[9]=fmaf(kc.y,ts,v[9]); v[10]=fmaf(kc.z,ts,v[10]); v[11]=fmaf(kc.w,ts,v[11]);
  }
}

__global__ void __launch_bounds__(512) setup_kernel(
    const float* __restrict__ t_eval, const float* __restrict__ A,
    const float* __restrict__ Bm, const float* __restrict__ loads_raw,
    const float* __restrict__ areas, float* ws) {
  __shared__ double H1[144], H2[144], H3[144], H4[144], Md[144];
  __shared__ double Qa[144], Qb[144];
  __shared__ double C256s[144], C512s[144], C1024s[144], C2048s[144];
  __shared__ double Pd1s[144], Pd2s[144], Pd4s[144], Pd8s[144];
  __shared__ double Pd3s[144], Pd5s[144], Pd6s[144], Pd7s[144];
  __shared__ double cd[12], ald[12], bed[12], b0d[12], bqd[12];
  __shared__ double Vv[3][12], Kd[72];
  int t = threadIdx.x;
  for (int f = t; f < NB; f += 512)            // reset lookback flags
    ((int*)(ws + OFF_FLAG))[f] = 0;
  double h = (double)t_eval[1] - (double)t_eval[0];
  if (t < 144) H1[t] = h * (double)A[t];
  if (t < 12) {
    b0d[t] = (double)Bm[t*11];
    double s = 0.0;
    for (int r = 0; r < 10; ++r) {
      double gq = 50.0 / (1.0 + exp(-(double)loads_raw[10 + r]));
      s += (double)Bm[t*11 + 1 + r] * (gq * (double)areas[r]);
    }
    bqd[t] = s;
  }
  if (t < 72) Kd[t] = 0.0;
  __syncthreads();
  if (t < 144) {                              // H2 = H1*H1
    int i=t/12, j=t%12; double s=0.0;
#pragma unroll
    for (int m = 0; m < 12; ++m) s += H1[i*12+m]*H1[m*12+j];
    H2[t]=s;
  }
  __syncthreads();
  if (t < 288) {                              // H3 = H2*H1 | H4 = H2*H2
    int w=t/144, e=t%144, i=e/12, j=e%12;
    const double* Bp = w ? H2 : H1;
    double s = 0.0;
#pragma unroll
    for (int m = 0; m < 12; ++m) s += H2[i*12+m]*Bp[m*12+j];
    (w ? H4 : H3)[e] = s;
  }
  __syncthreads();
  if (t < 12) {
    double hb=0,h2b=0,h3b=0,hb0=0,h2b0=0,h3b0=0;
#pragma unroll
    for (int m = 0; m < 12; ++m) {
      hb  += H1[t*12+m]*bqd[m]; h2b  += H2[t*12+m]*bqd[m]; h3b  += H3[t*12+m]*bqd[m];
      hb0 += H1[t*12+m]*b0d[m]; h2b0 += H2[t*12+m]*b0d[m]; h3b0 += H3[t*12+m]*b0d[m];
    }
    double h6 = h / 6.0;
    cd[t]  = h6*(6.0*bqd[t] + 3.0*hb + h2b + 0.25*h3b);
    ald[t] = h6*(3.0*b0d[t] + 2.0*hb0 + 0.75*h2b0 + 0.25*h3b0);
    bed[t] = h6*(3.0*b0d[t] + hb0 + 0.25*h2b0);
    Vv[0][t]=ald[t]; Vv[1][t]=bed[t]; Vv[2][t]=cd[t];
    // r=0 K contributions (CH=4): col4 += al, col5 += be, col0 += c
    Kd[48+t] += ald[t]; Kd[60+t] += bed[t]; Kd[t] += cd[t];
  }
  if (t >= 144 && t < 288) {
    int e=t-144, i=e/12, j=e%12;
    Md[e] = (i==j ? 1.0 : 0.0) + H1[e] + 0.5*H2[e] + H3[e]/6.0 + H4[e]/24.0;
  }
  __syncthreads();
  if (t < 144) { ws[OFF_M+t] = (float)Md[t]; Qa[t] = Md[t]; }
  if (t < 12) {
    ws[OFF_C+t]=(float)cd[t]; ws[OFF_AL+t]=(float)ald[t]; ws[OFF_BE+t]=(float)bed[t];
  }
  __syncthreads();
  // chain r=1..15: src=M^(2^(r-1)) -> dst=M^(2^r). Overlapped K rounds
  // r=1..3 (threads 256..291): Vv=M^r*{al,be,c}; Kd cols (4-r),(5-r),0.
  double* src = Qa; double* dst = Qb;
  for (int r = 1; r <= 15; ++r) {
    double acc = 0.0, ks = 0.0;
    if (t < 144) {
      int i=t/12, j=t%12;
#pragma unroll
      for (int m = 0; m < 12; ++m) acc += src[i*12+m]*src[m*12+j];
    }
    int w=0, i2=0;
    if (r <= 3 && t >= 256 && t < 292) {
      w=(t-256)/12; i2=(t-256)%12;
#pragma unroll
      for (int m = 0; m < 12; ++m) ks += Md[i2*12+m]*Vv[w][m];
    }
    __syncthreads();
    if (t < 144) {
      dst[t] = acc;
      if (r >= 2 && r <= 9) ws[OFF_P2+(r-2)*144+t] = (float)acc;  // M^4..M^512
      if (r == 8)  C256s[t]=acc;
      if (r == 9)  C512s[t]=acc;
      if (r == 10) { C1024s[t]=acc; ws[OFF_PL+t]        = (float)acc; }
      if (r == 11) { C2048s[t]=acc; ws[OFF_PL+144+t]    = (float)acc; }
      if (r == 12) { Pd1s[t]=acc;   ws[OFF_PD+144+t]    = (float)acc; }  // M^4096
      if (r == 13) { Pd2s[t]=acc;   ws[OFF_PD+2*144+t]  = (float)acc; }  // M^8192
      if (r == 14) { Pd4s[t]=acc;   ws[OFF_PD+4*144+t]  = (float)acc; }  // M^16384
      if (r == 15) { Pd8s[t]=acc;   ws[OFF_PD+8*144+t]  = (float)acc; }  // M^32768
    }
    if (r <= 3 && t >= 256 && t < 292) {
      Vv[w][i2] = ks;
      if (w == 0) Kd[(4-r)*12+i2] += ks;
      else if (w == 1) Kd[(5-r)*12+i2] += ks;
      else Kd[i2] += ks;
    }
    __syncthreads();
    double* tmp = src; src = dst; dst = tmp;    // src = M^(2^r)
  }
  if (t < 72) ws[OFF_K+t] = (float)Kd[t];
  if (t < 144) ws[OFF_PD+t] = (t % 13 == 0) ? 1.f : 0.f;   // Pd[0]=I
  // product round A: M^768=C256*C512 ; M^3072=C1024*C2048 ; Pd3=Pd1*Pd2
  if (t < 432) {
    int w=t/144, e=t%144, i=e/12, j=e%12;
    const double* Ap = (w==0) ? C256s : ((w==1) ? C1024s : Pd1s);
    const double* Bp = (w==0) ? C512s : ((w==1) ? C2048s : Pd2s);
    double s = 0.0;
#pragma unroll
    for (int m = 0; m < 12; ++m) s += Ap[i*12+m]*Bp[m*12+j];
    if (w==0) ws[OFF_PA+144+e] = (float)s;
    else if (w==1) ws[OFF_PL+2*144+e] = (float)s;
    else { ws[OFF_PD+3*144+e] = (float)s; Pd3s[e] = s; }
  }
  __syncthreads();
  // product round B: Pd5=Pd1*Pd4 ; Pd6=Pd2*Pd4 ; Pd7=Pd3*Pd4
  if (t < 432) {
    int w=t/144, e=t%144, i=e/12, j=e%12;
    const double* Ap = (w==0) ? Pd1s : ((w==1) ? Pd2s : Pd3s);
    double s = 0.0;
#pragma unroll
    for (int m = 0; m < 12; ++m) s += Ap[i*12+m]*Pd4s[m*12+j];
    ws[OFF_PD+(5+w)*144+e] = (float)s;
    (w==0 ? Pd5s : (w==1 ? Pd6s : Pd7s))[e] = s;
  }
  __syncthreads();
  // barrier-free batches: Pd9..Pd15 = {Pd1..Pd7}*Pd8
  if (t < 432) {
    int w=t/144, e=t%144, i=e/12, j=e%12;
    const double* Ap = (w==0) ? Pd1s : ((w==1) ? Pd2s : Pd3s);
    double s = 0.0;
#pragma unroll
    for (int m = 0; m < 12; ++m) s += Ap[i*12+m]*Pd8s[m*12+j];
    ws[OFF_PD+(9+w)*144+e] = (float)s;
  }
  if (t < 432) {
    int w=t/144, e=t%144, i=e/12, j=e%12;
    const double* Ap = (w==0) ? Pd4s : ((w==1) ? Pd5s : Pd6s);
    double s = 0.0;
#pragma unroll
    for (int m = 0; m < 12; ++m) s += Ap[i*12+m]*Pd8s[m*12+j];
    ws[OFF_PD+(12+w)*144+e] = (float)s;
  }
  if (t < 144) {
    int i=t/12, j=t%12;
    double s = 0.0;
#pragma unroll
    for (int m = 0; m < 12; ++m) s += Pd7s[i*12+m]*Pd8s[m*12+j];
    ws[OFF_PD+15*144+t] = (float)s;
  }
}

// Fused: LDS-mirror cons; fold+scan ONCE; agg tree; publish (vmcnt drain
// + RELAXED flag, no wbl2); RELAXED spin (no inv); lookback reads agg via
// relaxed atomic loads (LLC-direct, no fence); merged prefix + 4-step
// expand. Plain launch, graph-capturable. Zero cache-maintenance ops.
__global__ void __launch_bounds__(BLK, 4) fused_scan(
    const float* __restrict__ cons, const float* __restrict__ To,
    const float* __restrict__ x0, float* __restrict__ agg,
    int* __restrict__ flags, float* __restrict__ out) {
  __shared__ __align__(16) float Lc[NCONS];   // LDS mirror of cons
  __shared__ __align__(16) float Tw[48];      // wave totals
  __shared__ __align__(16) float Ta[24];      // agg tree level 1
  __shared__ __align__(16) float Pw[48];      // wave exclusive prefixes
  __shared__ __align__(16) float lkb[64*12];  // lookback stage-1 partials
  __shared__ __align__(16) float yv[16*12];
  __shared__ __align__(16) float zv[16*12];
  __shared__ __align__(16) float Xs[12];
  __shared__ __align__(16) float Qw[48];      // M^(256w)*Xs + Pw
  int k = threadIdx.x, b = blockIdx.x;
  int g = b*BLK + k, base = g*CH;
  bool active = (g < NCHUNK), fullc = (g <= LASTFULL);
  float to_[5];
#pragma unroll
  for (int i = 0; i < 5; ++i) to_[i] = 0.f;
  if (active) {
    const float4* tp = reinterpret_cast<const float4*>(To + base);
    float4 ta = tp[0];
    to_[0]=ta.x; to_[1]=ta.y; to_[2]=ta.z; to_[3]=ta.w;
    to_[4] = fullc ? To[base+4] : 0.f;
  }
  {                                  // mirror cons -> LDS (1110 float4)
    const float4* s4 = reinterpret_cast<const float4*>(cons);
    float4* d4 = reinterpret_cast<float4*>(Lc);
#pragma unroll
    for (int r = 0; r < 5; ++r) {
      int idx = k + r*BLK;
      if (idx < NCONS/4) d4[idx] = s4[idx];
    }
  }
  __syncthreads();
  const float* lc = Lc;              // all constant reads now LDS
  float v[12];
  if (fullc) fold_chunk(lc, to_, v);
  else {
#pragma unroll
    for (int i = 0; i < 12; ++i) v[i] = 0.f;
  }
  if (g == 0) {                      // fold x0 into chunk 0: v += M^4 x0
    float xi[12];
#pragma unroll
    for (int i = 0; i < 12; ++i) xi[i] = x0[i];
    mv_acc(lc + OFF_P2, xi, v);
  }
  int j = k & 63, w = k >> 6;
#pragma unroll
  for (int l = 0; l < 6; ++l) {      // in-wave inclusive scan
    int off = 1 << l;
    float nb[12];
#pragma unroll
    for (int i = 0; i < 12; ++i) nb[i] = __shfl_up(v[i], (unsigned)off, 64);
    if (j >= off) mv_acc(lc + OFF_P2 + l*144, nb, v);
  }
  float se[12];                      // exclusive in-wave scan
#pragma unroll
  for (int i = 0; i < 12; ++i) {
    float u = __shfl_up(v[i], 1u, 64);
    se[i] = (j == 0) ? 0.f : u;
  }
  if (j == 63) {
#pragma unroll
    for (int i = 0; i < 12; ++i) Tw[w*12 + i] = v[i];
  }
  __syncthreads();
  if (k < 24) {                      // (T0,T1),(T2,T3): M^256*left + right
    int p = k/12, comp = k - p*12;
    Ta[k] = rowdot(lc + OFF_P2 + 6*144 + comp*12, Tw + 2*p*12)
          + Tw[(2*p+1)*12 + comp];
  }
  __syncthreads();
  if (k < 12) {                      // agg[b] = M^512*Ta0 + Ta1 (sc1->LLC)
    float val = rowdot(lc + OFF_P2 + 7*144 + k*12, Ta) + Ta[12 + k];
    __hip_atomic_store(&agg[b*12 + k], val, __ATOMIC_RELAXED,
                       __HIP_MEMORY_SCOPE_AGENT);
  }
  __syncthreads();                   // barrier drains vmcnt (agg at LLC)
  asm volatile("s_waitcnt vmcnt(0)" ::: "memory");
  if (k == 0)                        // publish: RELAXED flag (no wbl2)
    __hip_atomic_store(&flags[b], 1, __ATOMIC_RELAXED,
                       __HIP_MEMORY_SCOPE_AGENT);
  // spin on 64 predecessors, RELAXED polls (sc1 LLC reads, no inv)
  if (k < 64) {
    int src = b - 1 - k;
    if (src >= 0) {
      while (__hip_atomic_load(&flags[src], __ATOMIC_RELAXED,
                               __HIP_MEMORY_SCOPE_AGENT) == 0) {
        __builtin_amdgcn_s_sleep(1);
      }
    }
  }
  __syncthreads();
  // lookback stage 1: slot=4i+jj: lkb[slot] = M^(1024*jj)*agg[b-1-slot];
  // agg read via relaxed atomic loads (LLC-direct, no fence needed)
#pragma unroll
  for (int r = 0; r < 3; ++r) {
    int idx = k + r*BLK;             // 768 = 3*BLK exactly
    int slot = idx / 12, comp = idx - slot*12;
    int src = b - 1 - slot;
    float acc = 0.f;
    if (src >= 0) {
      float agv[12];
#pragma unroll
      for (int q = 0; q < 12; ++q)
        agv[q] = __hip_atomic_load(&agg[src*12 + q], __ATOMIC_RELAXED,
                                   __HIP_MEMORY_SCOPE_AGENT);
      int jj = slot & 3;
      acc = (jj == 0) ? agv[comp]
          : rowdot(lc + OFF_PL + (jj-1)*144 + comp*12, agv);
    }
    lkb[idx] = acc;
  }
  __syncthreads();
  // yv[i] = sum_jj lkb[4i+jj]  (k<192)  |  Pw: P0=0, P1=T0  (k in [192,216))
  if (k < 192) {
    int i = k/12, comp = k - i*12;
    yv[k] = lkb[(4*i)*12+comp] + lkb[(4*i+1)*12+comp]
          + lkb[(4*i+2)*12+comp] + lkb[(4*i+3)*12+comp];
  } else if (k < 216) {
    int q = k - 192;                 // 0..23
    if (q < 12) Pw[q] = 0.f;         // P0
    else Pw[q] = Tw[q-12];           // P1 = T0
  }
  __syncthreads();
  // zv[i] = M^(4096i)*yv[i] (k<192) | P2 = M^256*P1 + T1 (k in [192,204))
  if (k < 192) {
    int i = k/12, comp = k - i*12;
    zv[k] = (i == 0) ? yv[comp]
          : rowdot(lc + OFF_PD + i*144 + comp*12, yv + i*12);
  } else if (k >= 192 && k < 204) {
    int comp = k - 192;
    Pw[24+comp] = rowdot(lc + OFF_P2 + 6*144 + comp*12, Pw+12) + Tw[12+comp];
  }
  __syncthreads();
  // Xs = sum_i zv[i] (k<12) | P3 = M^256*P2 + T2 (k in [192,204))
  if (k < 12) {
    float s = 0.f;
#pragma unroll
    for (int i = 0; i < 16; ++i) s += zv[i*12 + k];
    Xs[k] = s;
  } else if (k >= 192 && k < 204) {
    int comp = k - 192;
    Pw[36+comp] = rowdot(lc + OFF_P2 + 6*144 + comp*12, Pw+24) + Tw[24+comp];
  }
  __syncthreads();
  // Qw[w] = M^(256w)*Xs + Pw[w]  (w=0..3; matrices I, M^256, M^512, M^768)
  if (k < 48) {
    int ww = k/12, comp = k - ww*12;
    float acc;
    if (ww == 0) acc = Xs[comp];
    else if (ww == 1) acc = rowdot(lc + OFF_P2 + 6*144 + comp*12, Xs);
    else if (ww == 2) acc = rowdot(lc + OFF_P2 + 7*144 + comp*12, Xs);
    else acc = rowdot(lc + OFF_PA + 144 + comp*12, Xs);
    Qw[k] = acc + Pw[k];
  }
  __syncthreads();
  if (!active) return;               // all barriers done
  // per-thread: x = M^(4j)*Qw[w] + se   (bits of j, P2[0..5])
  float x[12];
#pragma unroll
  for (int i = 0; i < 12; ++i) x[i] = Qw[w*12 + i];
#pragma unroll
  for (int l = 0; l < 6; ++l) {
    if ((j >> l) & 1) {
      float vn[12];
#pragma unroll
      for (int i = 0; i < 12; ++i) vn[i] = 0.f;
      mv_acc(lc + OFF_P2 + l*144, x, vn);
#pragma unroll
      for (int i = 0; i < 12; ++i) x[i] = vn[i];
    }
  }
#pragma unroll
  for (int i = 0; i < 12; ++i) x[i] += se[i];
  if (b == 0 && k == 0) {
#pragma unroll
    for (int i = 0; i < 12; ++i) x[i] += x0[i];      // start state = x0
#pragma unroll
    for (int i = 0; i < 12; ++i) out[i] = x0[i];     // row 0
  }
  // expand: 4 unconditional steps, predicated stores (NO break).
  float cv[12], av[12], bv[12];
#pragma unroll
  for (int i = 0; i < 12; ++i) {
    cv[i] = lc[OFF_C + i]; av[i] = lc[OFF_AL + i]; bv[i] = lc[OFF_BE + i];
  }
  const float4* Mq = reinterpret_cast<const float4*>(lc + OFF_M);
#pragma unroll
  for (int s = 0; s < CH; ++s) {
    float tot = to_[s], ton = (s < CH-1) ? to_[s+1] : to_[4];
    float xn[12];
#pragma unroll
    for (int i = 0; i < 12; ++i) {
      float4 a = Mq[3*i], bq = Mq[3*i+1], c = Mq[3*i+2];
      xn[i] = FMA4(c, x[8],x[9],x[10],x[11],
               FMA4(bq, x[4],x[5],x[6],x[7],
                FMA4(a, x[0],x[1],x[2],x[3],
                 fmaf(bv[i],ton,fmaf(av[i],tot,cv[i])))));
    }
    int tt = base + s;
    if (tt < S_STEPS) {
      float4* op = reinterpret_cast<float4*>(out + (size_t)(tt+1)*12);
      op[0] = make_float4(xn[0],xn[1],xn[2],xn[3]);
      op[1] = make_float4(xn[4],xn[5],xn[6],xn[7]);
      op[2] = make_float4(xn[8],xn[9],xn[10],xn[11]);
    }
#pragma unroll
    for (int i = 0; i < 12; ++i) x[i] = xn[i];
  }
}

extern "C" void kernel_launch(void* const* d_in, const int* in_sizes, int n_in,
                              void* d_out, int out_size, void* d_ws, size_t ws_size,
                              hipStream_t stream) {
  const float* t_eval    = (const float*)d_in[0];
  const float* x0        = (const float*)d_in[1];
  const float* A         = (const float*)d_in[2];
  const float* B         = (const float*)d_in[3];
  const float* To        = (const float*)d_in[4];
  const float* loads_raw = (const float*)d_in[5];
  const float* areas     = (const float*)d_in[6];
  float* out = (float*)d_out;
  float* ws  = (float*)d_ws;

  setup_kernel<<<1, 512, 0, stream>>>(t_eval, A, B, loads_raw, areas, ws);
  fused_scan<<<NB, BLK, 0, stream>>>(ws, To, x0, ws + OFF_AGG,
                                     (int*)(ws + OFF_FLAG), out);
}

// Round 10
// 133.221 us; speedup vs baseline: 1.3046x; 1.1836x over previous
//
#include <hip/hip_runtime.h>
#include <math.h>

// RC thermal model: x' = A x + b0*To(t) + Bq, RK4 h=30, T=1e6 steps.
// Per step: x_{t+1} = M x_t + c + al*To[t] + be*To[t+1].
// R18: SINGLE-DISPATCH kernel. CH=4-fused abandoned (R16/R17: 2.6x WRITE
// / 15x FETCH regardless of atomic flavor; R17's per-scalar atomic agg
// loads alone = 36MB EA traffic). Base = R15 (CH=8 fused, clean: WRITE
// 66.8MB, FETCH 2.5MB, 51.3us). New: block 0 = setup (256-thread port);
// blocks 1..489 = verbatim R15 workers. Setup publishes in 2 stages via
// MAGIC flags (poison-proof): stage1 (M/C/AL/BE,K,P2) after chain r=10;
// stage2 (PA/PL/PD) after products. Workers: To->regs (overlaps setup),
// spin stage1 (relaxed+acquire-once), mirror stage1, fold/scan/publish
// (R15 verbatim), spin stage2 CONCURRENT with pred spins (k==32 vs k<32),
// mirror stage2, lookback/expand (R15 verbatim). Hides setup tail under
// scan; removes 2 launch gaps. Deadlock-free: 490 <= 512 capacity at
// (256,2); setup waits on nobody; workers publish before waiting.
// Cross-XCD visibility: stage release store (wbl2) + worker acquire-once
// -- the same pattern R15's agg/flag path proved.

#define S_STEPS 999999
#define CH      8
#define BLK     256
#define NB_W    489          // worker blocks; 489*256*8 >= S_STEPS
#define NCHUNK  125000       // active chunks (last partial: 7 steps)
#define LASTFULL 124998      // g <= LASTFULL: To[8g+8] in bounds

// ws float offsets (16B-aligned) -- R15 layout
#define OFF_M   0            // 144: M
#define OFF_C   144          // 12
#define OFF_AL  156          // 12
#define OFF_BE  168          // 12
#define OFF_K   192          // 120: K cols [col][12] (10 cols)
#define OFF_P2  320          // 8*144: [l]=M^(8*2^l) l=0..5, [6]=M^512, [7]=M^1024
#define OFF_PA  1472         // 144: M^1536            <- stage2 starts here
#define OFF_PL  1616         // 3*144: M^2048, M^4096, M^6144
#define OFF_PD  2048         // 8*144: Pd[i]=M^(8192*i), i=0..7
#define NCONS   3200         // floats mirrored to LDS
#define NS1Q    368          // stage-1 float4 count (1472/4)
#define NS2Q    432          // stage-2 float4 count ((3200-1472)/4)
#define OFF_AGG 3200         // 489*12 aggregates (end 9068)
#define OFF_FLAG 9072        // 489 int flags
#define OFF_SFLAG 9568       // 2 int stage flags (16B aligned)
#define MAGIC1  0x1357ACE9
#define MAGIC2  0x2468BDF1

#define FMA4(Q,a,b,c,d,acc) fmaf((Q).w,(d),fmaf((Q).z,(c),fmaf((Q).y,(b),fmaf((Q).x,(a),(acc)))))

// y += P(12x12 row-major, 16B-aligned) * x
__device__ __forceinline__ void mv_acc(const float* Pf, const float* x, float* y) {
  const float4* P = reinterpret_cast<const float4*>(Pf);
#pragma unroll
  for (int i = 0; i < 12; ++i) {
    float4 a = P[3*i], b = P[3*i+1], c = P[3*i+2];
    y[i] = FMA4(c, x[8],x[9],x[10],x[11],
            FMA4(b, x[4],x[5],x[6],x[7],
             FMA4(a, x[0],x[1],x[2],x[3], y[i])));
  }
}

// dot(P row (16B-aligned), xv[0..11] scalars)
__device__ __forceinline__ float rowdot(const float* Prow, const float* xv) {
  const float4* P = reinterpret_cast<const float4*>(Prow);
  float4 a = P[0], b = P[1], c = P[2];
  return FMA4(c, xv[8],xv[9],xv[10],xv[11],
          FMA4(b, xv[4],xv[5],xv[6],xv[7],
           FMA4(a, xv[0],xv[1],xv[2],xv[3], 0.f)));
}

// v = K[:,0] + sum_{s=0..8} K[:,s+1]*tos[s]
__device__ __forceinline__ void fold_chunk(const float* cons,
                                           const float* tos, float* v) {
  const float4* Kq = reinterpret_cast<const float4*>(cons + OFF_K);
  float4 c0=Kq[0], c1=Kq[1], c2=Kq[2];
  v[0]=c0.x; v[1]=c0.y; v[2]=c0.z; v[3]=c0.w;
  v[4]=c1.x; v[5]=c1.y; v[6]=c1.z; v[7]=c1.w;
  v[8]=c2.x; v[9]=c2.y; v[10]=c2.z; v[11]=c2.w;
#pragma unroll
  for (int s = 0; s < 9; ++s) {
    float ts = tos[s];
    float4 ka=Kq[3*(s+1)], kb=Kq[3*(s+1)+1], kc=Kq[3*(s+1)+2];
    v[0]=fmaf(ka.x,ts,v[0]); v[1]=fmaf(ka.y,ts,v[1]); v[2]=fmaf(ka.z,ts,v[2]); v[3]=fmaf(ka.w,ts,v[3]);
    v[4]=fmaf(kb.x,ts,v[4]); v[5]=fmaf(kb.y,ts,v[5]); v[6]=fmaf(kb.z,ts,v[6]); v[7]=fmaf(kb.w,ts,v[7]);
    v[8]=fmaf(kc.x,ts,v[8]); v[9]=fmaf(kc.y,ts,v[9]); v[10]=fmaf(kc.z,ts,v[10]); v[11]=fmaf(kc.w,ts,v[11]);
  }
}

__global__ void __launch_bounds__(BLK, 2) fused_all(
    const float* __restrict__ t_eval, const float* __restrict__ A,
    const float* __restrict__ Bm, const float* __restrict__ loads_raw,
    const float* __restrict__ areas,
    float* ws, const float* __restrict__ To,
    const float* __restrict__ x0, float* __restrict__ out) {
  // ---- worker shared ----
  __shared__ __align__(16) float Lc[NCONS];
  __shared__ __align__(16) float Tw[48];
  __shared__ __align__(16) float Ta[24];
  __shared__ __align__(16) float Pw[48];
  __shared__ __align__(16) float lkb[32*12];
  __shared__ __align__(16) float yv[8*12];
  __shared__ __align__(16) float zv[8*12];
  __shared__ __align__(16) float Xs[12];
  __shared__ __align__(16) float Qw[48];
  // ---- setup shared (block 0 only) ----
  __shared__ double H1[144], H2[144], H3[144], H4[144], Md[144];
  __shared__ double Qa[144], Qb[144];
  __shared__ double C512s[144], C1024s[144], C2048s[144], C4096s[144];
  __shared__ double C8192s[144], C16384s[144], C32768s[144], Pd3s[144];
  __shared__ double cd[12], ald[12], bed[12], b0d[12], bqd[12];
  __shared__ double Vv[3][12], Kd[120];

  int k = threadIdx.x;
  float* agg   = ws + OFF_AGG;
  int*   flags = (int*)(ws + OFF_FLAG);
  int*   sflag = (int*)(ws + OFF_SFLAG);

  if (blockIdx.x == 0) {
    // ================= SETUP BLOCK (256 threads) =================
    int t = k;
    for (int f = t; f < NB_W; f += BLK) flags[f] = 0;   // zero pred flags
    double h = (double)t_eval[1] - (double)t_eval[0];
    if (t < 144) H1[t] = h * (double)A[t];
    if (t < 12) {
      b0d[t] = (double)Bm[t*11];
      double s = 0.0;
      for (int r = 0; r < 10; ++r) {
        double gq = 50.0 / (1.0 + exp(-(double)loads_raw[10 + r]));
        s += (double)Bm[t*11 + 1 + r] * (gq * (double)areas[r]);
      }
      bqd[t] = s;
    }
    if (t < 120) Kd[t] = 0.0;
    __syncthreads();
    if (t < 144) {                              // H2 = H1*H1
      int i=t/12, j=t%12; double s=0.0;
#pragma unroll
      for (int m = 0; m < 12; ++m) s += H1[i*12+m]*H1[m*12+j];
      H2[t]=s;
    }
    __syncthreads();
    for (int e2 = t; e2 < 288; e2 += BLK) {     // H3 = H2*H1 | H4 = H2*H2
      int w=e2/144, e=e2%144, i=e/12, j=e%12;
      const double* Bp = w ? H2 : H1;
      double s = 0.0;
#pragma unroll
      for (int m = 0; m < 12; ++m) s += H2[i*12+m]*Bp[m*12+j];
      (w ? H4 : H3)[e] = s;
    }
    __syncthreads();
    if (t < 12) {
      double hb=0,h2b=0,h3b=0,hb0=0,h2b0=0,h3b0=0;
#pragma unroll
      for (int m = 0; m < 12; ++m) {
        hb  += H1[t*12+m]*bqd[m]; h2b  += H2[t*12+m]*bqd[m]; h3b  += H3[t*12+m]*bqd[m];
        hb0 += H1[t*12+m]*b0d[m]; h2b0 += H2[t*12+m]*b0d[m]; h3b0 += H3[t*12+m]*b0d[m];
      }
      double h6 = h / 6.0;
      cd[t]  = h6*(6.0*bqd[t] + 3.0*hb + h2b + 0.25*h3b);
      ald[t] = h6*(3.0*b0d[t] + 2.0*hb0 + 0.75*h2b0 + 0.25*h3b0);
      bed[t] = h6*(3.0*b0d[t] + hb0 + 0.25*h2b0);
      Vv[0][t]=ald[t]; Vv[1][t]=bed[t]; Vv[2][t]=cd[t];
      // r=0 K contributions (CH=8): col8 += al, col9 += be, col0 += c
      Kd[96+t] += ald[t]; Kd[108+t] += bed[t]; Kd[t] += cd[t];
    }
    if (t < 144) {                              // Md (threads 0..143)
      int i=t/12, j=t%12;
      Md[t] = (i==j ? 1.0 : 0.0) + H1[t] + 0.5*H2[t] + H3[t]/6.0 + H4[t]/24.0;
    }
    __syncthreads();
    if (t < 144) { ws[OFF_M+t] = (float)Md[t]; Qa[t] = Md[t]; }
    if (t < 12) {
      ws[OFF_C+t]=(float)cd[t]; ws[OFF_AL+t]=(float)ald[t]; ws[OFF_BE+t]=(float)bed[t];
    }
    __syncthreads();
    // chain r=1..15: src=M^(2^(r-1)) -> dst=M^(2^r). K rounds r=1..7
    // on threads 144..179: Vv=M^r*{al,be,c}; Kd cols (8-r),(9-r),0.
    double* src = Qa; double* dst = Qb;
    for (int r = 1; r <= 15; ++r) {
      double acc = 0.0, ks = 0.0;
      if (t < 144) {
        int i=t/12, j=t%12;
#pragma unroll
        for (int m = 0; m < 12; ++m) acc += src[i*12+m]*src[m*12+j];
      }
      int w=0, i2=0;
      if (r <= 7 && t >= 144 && t < 180) {
        w=(t-144)/12; i2=(t-144)%12;
#pragma unroll
        for (int m = 0; m < 12; ++m) ks += Md[i2*12+m]*Vv[w][m];
      }
      __syncthreads();
      if (t < 144) {
        dst[t] = acc;
        if (r >= 3 && r <= 8) ws[OFF_P2+(r-3)*144+t] = (float)acc;  // M^8..M^256
        if (r == 9)  { ws[OFF_P2+6*144+t] = (float)acc; C512s[t]=acc; }
        if (r == 10) { ws[OFF_P2+7*144+t] = (float)acc; C1024s[t]=acc; }
        if (r == 11) { ws[OFF_PL+t]       = (float)acc; C2048s[t]=acc; }
        if (r == 12) { ws[OFF_PL+144+t]   = (float)acc; C4096s[t]=acc; }
        if (r == 13) { ws[OFF_PD+144+t]   = (float)acc; C8192s[t]=acc; }
        if (r == 14) { ws[OFF_PD+2*144+t] = (float)acc; C16384s[t]=acc; }
        if (r == 15) { ws[OFF_PD+4*144+t] = (float)acc; C32768s[t]=acc; }
        if (r == 8)  ws[OFF_PD+t] = (t % 13 == 0) ? 1.f : 0.f;      // Pd[0]=I
      }
      if (r <= 7 && t >= 144 && t < 180) {
        Vv[w][i2] = ks;
        if (w == 0) Kd[(8-r)*12+i2] += ks;
        else if (w == 1) Kd[(9-r)*12+i2] += ks;
        else Kd[i2] += ks;
      }
      if (r == 8 && t < 120) ws[OFF_K+t] = (float)Kd[t];  // K done at r=7
      __syncthreads();
      double* tmp = src; src = dst; dst = tmp;    // src = M^(2^r)
      if (r == 10 && t == 0)                      // STAGE 1: scan-ready
        __hip_atomic_store(&sflag[0], MAGIC1, __ATOMIC_RELEASE,
                           __HIP_MEMORY_SCOPE_AGENT);
    }
    // product round A: M^1536=C512*C1024 ; M^6144=C2048*C4096 ;
    //                  Pd3=C8192*C16384
    for (int idx = t; idx < 432; idx += BLK) {
      int w=idx/144, e=idx%144, i=e/12, j=e%12;
      const double* Ap = (w==0) ? C512s  : ((w==1) ? C2048s : C8192s);
      const double* Bp = (w==0) ? C1024s : ((w==1) ? C4096s : C16384s);
      double s = 0.0;
#pragma unroll
      for (int m = 0; m < 12; ++m) s += Ap[i*12+m]*Bp[m*12+j];
      if (w==0) ws[OFF_PA+e] = (float)s;
      else if (w==1) ws[OFF_PL+2*144+e] = (float)s;
      else { ws[OFF_PD+3*144+e] = (float)s; Pd3s[e] = s; }
    }
    __syncthreads();
    // product round B: Pd5=Pd1*Pd4 ; Pd6=Pd2*Pd4 ; Pd7=Pd3*Pd4
    for (int idx = t; idx < 432; idx += BLK) {
      int w=idx/144, e=idx%144, i=e/12, j=e%12;
      const double* Ap = (w==0) ? C8192s : ((w==1) ? C16384s : Pd3s);
      double s = 0.0;
#pragma unroll
      for (int m = 0; m < 12; ++m) s += Ap[i*12+m]*C32768s[m*12+j];
      ws[OFF_PD+(5+w)*144+e] = (float)s;
    }
    __syncthreads();
    if (t == 0)                                   // STAGE 2: lookback-ready
      __hip_atomic_store(&sflag[1], MAGIC2, __ATOMIC_RELEASE,
                         __HIP_MEMORY_SCOPE_AGENT);
    return;
  }

  // ================= WORKER BLOCKS (verbatim R15 + staging) =================
  int b = blockIdx.x - 1;
  int g = b*BLK + k, base = g*CH;
  bool active = (g < NCHUNK), fullc = (g <= LASTFULL);
  float to_[9];
#pragma unroll
  for (int i = 0; i < 9; ++i) to_[i] = 0.f;
  if (active) {                      // To loads overlap setup
    const float4* tp = reinterpret_cast<const float4*>(To + base);
    float4 ta = tp[0], tb = tp[1];
    to_[0]=ta.x; to_[1]=ta.y; to_[2]=ta.z; to_[3]=ta.w;
    to_[4]=tb.x; to_[5]=tb.y; to_[6]=tb.z; to_[7]=tb.w;
    to_[8] = fullc ? To[base+8] : 0.f;
  }
  // stage-1 spin (relaxed polls + one acquire)
  if (k == 0) {
    while (__hip_atomic_load(&sflag[0], __ATOMIC_RELAXED,
                             __HIP_MEMORY_SCOPE_AGENT) != MAGIC1)
      __builtin_amdgcn_s_sleep(8);
    (void)__hip_atomic_load(&sflag[0], __ATOMIC_ACQUIRE,
                            __HIP_MEMORY_SCOPE_AGENT);
  }
  __syncthreads();
  {                                  // mirror stage-1: cons[0..1472)
    const float4* s4 = reinterpret_cast<const float4*>(ws);
    float4* d4 = reinterpret_cast<float4*>(Lc);
#pragma unroll
    for (int r = 0; r < 2; ++r) {
      int idx = k + r*BLK;
      if (idx < NS1Q) d4[idx] = s4[idx];
    }
  }
  __syncthreads();
  const float* lc = Lc;
  float v[12];
  if (fullc) fold_chunk(lc, to_, v);
  else {
#pragma unroll
    for (int i = 0; i < 12; ++i) v[i] = 0.f;
  }
  if (g == 0) {                      // fold x0 into chunk 0: v += M^8 x0
    float xi[12];
#pragma unroll
    for (int i = 0; i < 12; ++i) xi[i] = x0[i];
    mv_acc(lc + OFF_P2, xi, v);
  }
  int j = k & 63, w = k >> 6;
#pragma unroll
  for (int l = 0; l < 6; ++l) {      // in-wave inclusive scan
    int off = 1 << l;
    float nb[12];
#pragma unroll
    for (int i = 0; i < 12; ++i) nb[i] = __shfl_up(v[i], (unsigned)off, 64);
    if (j >= off) mv_acc(lc + OFF_P2 + l*144, nb, v);
  }
  float se[12];                      // exclusive in-wave scan
#pragma unroll
  for (int i = 0; i < 12; ++i) {
    float u = __shfl_up(v[i], 1u, 64);
    se[i] = (j == 0) ? 0.f : u;
  }
  if (j == 63) {
#pragma unroll
    for (int i = 0; i < 12; ++i) Tw[w*12 + i] = v[i];
  }
  __syncthreads();
  if (k < 24) {                      // (T0,T1),(T2,T3): M^512*left + right
    int p = k/12, comp = k - p*12;
    Ta[k] = rowdot(lc + OFF_P2 + 6*144 + comp*12, Tw + 2*p*12)
          + Tw[(2*p+1)*12 + comp];
  }
  __syncthreads();
  if (k < 12) {                      // agg[b] = M^1024*Ta0 + Ta1 (agent)
    float val = rowdot(lc + OFF_P2 + 7*144 + k*12, Ta) + Ta[12 + k];
    __hip_atomic_store(&agg[b*12 + k], val, __ATOMIC_RELAXED,
                       __HIP_MEMORY_SCOPE_AGENT);
  }
  __syncthreads();
  if (k == 0)                        // publish: release flag
    __hip_atomic_store(&flags[b], 1, __ATOMIC_RELEASE,
                       __HIP_MEMORY_SCOPE_AGENT);
  // pred spins (k<32) CONCURRENT with stage-2 spin (k==32)
  if (k < 32) {
    int src = b - 1 - k;
    if (src >= 0) {
      while (__hip_atomic_load(&flags[src], __ATOMIC_ACQUIRE,
                               __HIP_MEMORY_SCOPE_AGENT) == 0) {
        __builtin_amdgcn_s_sleep(1);
      }
    }
  } else if (k == 32) {
    while (__hip_atomic_load(&sflag[1], __ATOMIC_RELAXED,
                             __HIP_MEMORY_SCOPE_AGENT) != MAGIC2)
      __builtin_amdgcn_s_sleep(2);
    (void)__hip_atomic_load(&sflag[1], __ATOMIC_ACQUIRE,
                            __HIP_MEMORY_SCOPE_AGENT);
  }
  __syncthreads();
  {                                  // mirror stage-2: cons[1472..3200)
    const float4* s4 = reinterpret_cast<const float4*>(ws);
    float4* d4 = reinterpret_cast<float4*>(Lc);
#pragma unroll
    for (int r = 0; r < 2; ++r) {
      int idx = k + r*BLK;
      if (idx < NS2Q) d4[NS1Q + idx] = s4[NS1Q + idx];
    }
  }
  __syncthreads();
  // lookback stage 1: slot=4i+jj: lkb[slot] = M^(2048*jj)*agg[b-1-slot]
#pragma unroll
  for (int r = 0; r < 2; ++r) {
    int idx = k + r*BLK;             // covers 384 = 32*12
    if (idx < 384) {
      int slot = idx / 12, comp = idx - slot*12;
      int src = b - 1 - slot;
      float acc = 0.f;
      if (src >= 0) {
        int jj = slot & 3;
        const float* ag = agg + src*12;
        acc = (jj == 0) ? ag[comp]
            : rowdot(lc + OFF_PL + (jj-1)*144 + comp*12, ag);
      }
      lkb[idx] = acc;
    }
  }
  __syncthreads();
  // yv[i] = sum_jj lkb[4i+jj]  (k<96)  |  Pw: P0=0, P1=T0  (k in [192,216))
  if (k < 96) {
    int i = k/12, comp = k - i*12;
    yv[k] = lkb[(4*i)*12+comp] + lkb[(4*i+1)*12+comp]
          + lkb[(4*i+2)*12+comp] + lkb[(4*i+3)*12+comp];
  } else if (k >= 192 && k < 216) {
    int q = k - 192;                 // 0..23
    if (q < 12) Pw[q] = 0.f;         // P0
    else Pw[q] = Tw[q-12];           // P1 = T0
  }
  __syncthreads();
  // zv[i] = M^(8192i)*yv[i] (k<96) | P2 = M^512*P1 + T1 (k in [192,204))
  if (k < 96) {
    int i = k/12, comp = k - i*12;
    zv[k] = (i == 0) ? yv[comp]
          : rowdot(lc + OFF_PD + i*144 + comp*12, yv + i*12);
  } else if (k >= 192 && k < 204) {
    int comp = k - 192;
    Pw[24+comp] = rowdot(lc + OFF_P2 + 6*144 + comp*12, Pw+12) + Tw[12+comp];
  }
  __syncthreads();
  // Xs = sum_i zv[i] (k<12) | P3 = M^512*P2 + T2 (k in [192,204))
  if (k < 12) {
    float s = 0.f;
#pragma unroll
    for (int i = 0; i < 8; ++i) s += zv[i*12 + k];
    Xs[k] = s;
  } else if (k >= 192 && k < 204) {
    int comp = k - 192;
    Pw[36+comp] = rowdot(lc + OFF_P2 + 6*144 + comp*12, Pw+24) + Tw[24+comp];
  }
  __syncthreads();
  // Qw[w] = M^(512w)*Xs + Pw[w]  (w=0..3; matrices I, M^512, M^1024, M^1536)
  if (k < 48) {
    int ww = k/12, comp = k - ww*12;
    float acc;
    if (ww == 0) acc = Xs[comp];
    else if (ww == 1) acc = rowdot(lc + OFF_P2 + 6*144 + comp*12, Xs);
    else if (ww == 2) acc = rowdot(lc + OFF_P2 + 7*144 + comp*12, Xs);
    else acc = rowdot(lc + OFF_PA + comp*12, Xs);
    Qw[k] = acc + Pw[k];
  }
  __syncthreads();
  if (!active) return;               // all barriers done
  // per-thread: x = M^(8j)*Qw[w] + se   (bits of j, P2[0..5])
  float x[12];
#pragma unroll
  for (int i = 0; i < 12; ++i) x[i] = Qw[w*12 + i];
#pragma unroll
  for (int l = 0; l < 6; ++l) {
    if ((j >> l) & 1) {
      float vn[12];
#pragma unroll
      for (int i = 0; i < 12; ++i) vn[i] = 0.f;
      mv_acc(lc + OFF_P2 + l*144, x, vn);
#pragma unroll
      for (int i = 0; i < 12; ++i) x[i] = vn[i];
    }
  }
#pragma unroll
  for (int i = 0; i < 12; ++i) x[i] += se[i];
  if (b == 0 && k == 0) {
#pragma unroll
    for (int i = 0; i < 12; ++i) x[i] += x0[i];      // start state = x0
#pragma unroll
    for (int i = 0; i < 12; ++i) out[i] = x0[i];     // row 0
  }
  // expand: 8 unconditional steps, predicated stores (NO break)
  float cv[12], av[12], bv[12];
#pragma unroll
  for (int i = 0; i < 12; ++i) {
    cv[i] = lc[OFF_C + i]; av[i] = lc[OFF_AL + i]; bv[i] = lc[OFF_BE + i];
  }
  const float4* Mq = reinterpret_cast<const float4*>(lc + OFF_M);
#pragma unroll
  for (int s = 0; s < CH; ++s) {
    float tot = to_[s], ton = to_[s+1];
    float xn[12];
#pragma unroll
    for (int i = 0; i < 12; ++i) {
      float4 a = Mq[3*i], bq = Mq[3*i+1], c = Mq[3*i+2];
      xn[i] = FMA4(c, x[8],x[9],x[10],x[11],
               FMA4(bq, x[4],x[5],x[6],x[7],
                FMA4(a, x[0],x[1],x[2],x[3],
                 fmaf(bv[i],ton,fmaf(av[i],tot,cv[i])))));
    }
    int tt = base + s;
    if (tt < S_STEPS) {
      float4* op = reinterpret_cast<float4*>(out + (size_t)(tt+1)*12);
      op[0] = make_float4(xn[0],xn[1],xn[2],xn[3]);
      op[1] = make_float4(xn[4],xn[5],xn[6],xn[7]);
      op[2] = make_float4(xn[8],xn[9],xn[10],xn[11]);
    }
#pragma unroll
    for (int i = 0; i < 12; ++i) x[i] = xn[i];
  }
}

extern "C" void kernel_launch(void* const* d_in, const int* in_sizes, int n_in,
                              void* d_out, int out_size, void* d_ws, size_t ws_size,
                              hipStream_t stream) {
  const float* t_eval    = (const float*)d_in[0];
  const float* x0        = (const float*)d_in[1];
  const float* A         = (const float*)d_in[2];
  const float* B         = (const float*)d_in[3];
  const float* To        = (const float*)d_in[4];
  const float* loads_raw = (const float*)d_in[5];
  const float* areas     = (const float*)d_in[6];
  float* out = (float*)d_out;
  float* ws  = (float*)d_ws;

  fused_all<<<NB_W + 1, BLK, 0, stream>>>(t_eval, A, B, loads_raw, areas,
                                          ws, To, x0, out);
}

// Round 11
// 132.180 us; speedup vs baseline: 1.3149x; 1.0079x over previous
//
#include <hip/hip_runtime.h>
#include <math.h>

// RC thermal model: x' = A x + b0*To(t) + Bq, RK4 h=30, T=1e6 steps.
// Per step: x_{t+1} = M x_t + c + al*To[t] + be*To[t+1].
// R19: R18 single-dispatch base + 3 critical-path cuts (math identical):
//  1) stage-1 split: S1a after r=7 (K+P2[0..4] -> fold+levels0..4 start
//     ~3 setup rounds earlier); S1b after r=10 (P2[5..7] for level5+tree).
//  2) no stage-2 mirror: PA/PL/PD read from GLOBAL ws at lookback (few
//     reads, L2-resident); k==32 spins sflagC for readiness only.
//     Lc shrinks 12.8->5.9KB.
//  3) expand M hoisted into 36 NAMED float4 locals (no array -> no R12
//     scratch demotion; ~210 VGPR < 256 cap at 2 waves/SIMD). Removes
//     288 broadcast ds_read_b128 from the 8-step dependent chain.
// R18 lessons kept: CH=8 (CH=4 traffic explosion, R16/R17), publish/spin
// (grid.sync 50us, R11), LDS constants (vmcnt decoupling, R14/15).
// Deadlock-free: 490 blocks <= 512 capacity at (256,2); setup waits on
// nobody; workers publish before waiting; flags zeroed before S1a release
// (release wbl2 orders zero-stores before MAGICA visibility).

#define S_STEPS 999999
#define CH      8
#define BLK     256
#define NB_W    489          // worker blocks; 489*256*8 >= S_STEPS
#define NCHUNK  125000       // active chunks (last partial: 7 steps)
#define LASTFULL 124998      // g <= LASTFULL: To[8g+8] in bounds

// ws float offsets (16B-aligned)
#define OFF_M   0            // 144: M
#define OFF_C   144          // 12
#define OFF_AL  156          // 12
#define OFF_BE  168          // 12
#define OFF_K   192          // 120: K cols [col][12] (10 cols)
#define OFF_P2  320          // 8*144: [l]=M^(8*2^l) l=0..5, [6]=M^512, [7]=M^1024
#define OFF_PA  1472         // 144: M^1536
#define OFF_PL  1616         // 3*144: M^2048, M^4096, M^6144
#define OFF_PD  2048         // 8*144: Pd[i]=M^(8192*i), i=0..7
#define NLC     1472         // floats mirrored to LDS (stage 1a+1b)
#define NS1AQ   260          // stage-1a float4 count ([0,1040))
#define NS1BQ   108          // stage-1b float4 count ([1040,1472))
#define OFF_AGG 3200         // 489*12 aggregates (end 9068)
#define OFF_FLAG 9072        // 489 int flags
#define OFF_SFLAG 9568       // 3 int stage flags
#define MAGICA  0x1357ACE9
#define MAGICB  0x2468BDF1
#define MAGICC  0x369CF258

#define FMA4(Q,a,b,c,d,acc) fmaf((Q).w,(d),fmaf((Q).z,(c),fmaf((Q).y,(b),fmaf((Q).x,(a),(acc)))))

// y += P(12x12 row-major, 16B-aligned) * x
__device__ __forceinline__ void mv_acc(const float* Pf, const float* x, float* y) {
  const float4* P = reinterpret_cast<const float4*>(Pf);
#pragma unroll
  for (int i = 0; i < 12; ++i) {
    float4 a = P[3*i], b = P[3*i+1], c = P[3*i+2];
    y[i] = FMA4(c, x[8],x[9],x[10],x[11],
            FMA4(b, x[4],x[5],x[6],x[7],
             FMA4(a, x[0],x[1],x[2],x[3], y[i])));
  }
}

// dot(P row (16B-aligned), xv[0..11] scalars)
__device__ __forceinline__ float rowdot(const float* Prow, const float* xv) {
  const float4* P = reinterpret_cast<const float4*>(Prow);
  float4 a = P[0], b = P[1], c = P[2];
  return FMA4(c, xv[8],xv[9],xv[10],xv[11],
          FMA4(b, xv[4],xv[5],xv[6],xv[7],
           FMA4(a, xv[0],xv[1],xv[2],xv[3], 0.f)));
}

// v = K[:,0] + sum_{s=0..8} K[:,s+1]*tos[s]
__device__ __forceinline__ void fold_chunk(const float* cons,
                                           const float* tos, float* v) {
  const float4* Kq = reinterpret_cast<const float4*>(cons + OFF_K);
  float4 c0=Kq[0], c1=Kq[1], c2=Kq[2];
  v[0]=c0.x; v[1]=c0.y; v[2]=c0.z; v[3]=c0.w;
  v[4]=c1.x; v[5]=c1.y; v[6]=c1.z; v[7]=c1.w;
  v[8]=c2.x; v[9]=c2.y; v[10]=c2.z; v[11]=c2.w;
#pragma unroll
  for (int s = 0; s < 9; ++s) {
    float ts = tos[s];
    float4 ka=Kq[3*(s+1)], kb=Kq[3*(s+1)+1], kc=Kq[3*(s+1)+2];
    v[0]=fmaf(ka.x,ts,v[0]); v[1]=fmaf(ka.y,ts,v[1]); v[2]=fmaf(ka.z,ts,v[2]); v[3]=fmaf(ka.w,ts,v[3]);
    v[4]=fmaf(kb.x,ts,v[4]); v[5]=fmaf(kb.y,ts,v[5]); v[6]=fmaf(kb.z,ts,v[6]); v[7]=fmaf(kb.w,ts,v[7]);
    v[8]=fmaf(kc.x,ts,v[8]); v[9]=fmaf(kc.y,ts,v[9]); v[10]=fmaf(kc.z,ts,v[10]); v[11]=fmaf(kc.w,ts,v[11]);
  }
}

__global__ void __launch_bounds__(BLK, 2) fused_all(
    const float* __restrict__ t_eval, const float* __restrict__ A,
    const float* __restrict__ Bm, const float* __restrict__ loads_raw,
    const float* __restrict__ areas,
    float* ws, const float* __restrict__ To,
    const float* __restrict__ x0, float* __restrict__ out) {
  // ---- worker shared ----
  __shared__ __align__(16) float Lc[NLC];
  __shared__ __align__(16) float Tw[48];
  __shared__ __align__(16) float Ta[24];
  __shared__ __align__(16) float Pw[48];
  __shared__ __align__(16) float lkb[32*12];
  __shared__ __align__(16) float yv[8*12];
  __shared__ __align__(16) float zv[8*12];
  __shared__ __align__(16) float Xs[12];
  __shared__ __align__(16) float Qw[48];
  // ---- setup shared (block 0 only) ----
  __shared__ double H1[144], H2[144], H3[144], H4[144], Md[144];
  __shared__ double Qa[144], Qb[144];
  __shared__ double C512s[144], C1024s[144], C2048s[144], C4096s[144];
  __shared__ double C8192s[144], C16384s[144], C32768s[144], Pd3s[144];
  __shared__ double cd[12], ald[12], bed[12], b0d[12], bqd[12];
  __shared__ double Vv[3][12], Kd[120];

  int k = threadIdx.x;
  float* agg   = ws + OFF_AGG;
  int*   flags = (int*)(ws + OFF_FLAG);
  int*   sflag = (int*)(ws + OFF_SFLAG);

  if (blockIdx.x == 0) {
    // ================= SETUP BLOCK (256 threads) =================
    int t = k;
    for (int f = t; f < NB_W; f += BLK) flags[f] = 0;   // zero pred flags
    double h = (double)t_eval[1] - (double)t_eval[0];
    if (t < 144) H1[t] = h * (double)A[t];
    if (t < 12) {
      b0d[t] = (double)Bm[t*11];
      double s = 0.0;
      for (int r = 0; r < 10; ++r) {
        double gq = 50.0 / (1.0 + exp(-(double)loads_raw[10 + r]));
        s += (double)Bm[t*11 + 1 + r] * (gq * (double)areas[r]);
      }
      bqd[t] = s;
    }
    if (t < 120) Kd[t] = 0.0;
    __syncthreads();
    if (t < 144) {                              // H2 = H1*H1
      int i=t/12, j=t%12; double s=0.0;
#pragma unroll
      for (int m = 0; m < 12; ++m) s += H1[i*12+m]*H1[m*12+j];
      H2[t]=s;
    }
    __syncthreads();
    for (int e2 = t; e2 < 288; e2 += BLK) {     // H3 = H2*H1 | H4 = H2*H2
      int w=e2/144, e=e2%144, i=e/12, j=e%12;
      const double* Bp = w ? H2 : H1;
      double s = 0.0;
#pragma unroll
      for (int m = 0; m < 12; ++m) s += H2[i*12+m]*Bp[m*12+j];
      (w ? H4 : H3)[e] = s;
    }
    __syncthreads();
    if (t < 12) {
      double hb=0,h2b=0,h3b=0,hb0=0,h2b0=0,h3b0=0;
#pragma unroll
      for (int m = 0; m < 12; ++m) {
        hb  += H1[t*12+m]*bqd[m]; h2b  += H2[t*12+m]*bqd[m]; h3b  += H3[t*12+m]*bqd[m];
        hb0 += H1[t*12+m]*b0d[m]; h2b0 += H2[t*12+m]*b0d[m]; h3b0 += H3[t*12+m]*b0d[m];
      }
      double h6 = h / 6.0;
      cd[t]  = h6*(6.0*bqd[t] + 3.0*hb + h2b + 0.25*h3b);
      ald[t] = h6*(3.0*b0d[t] + 2.0*hb0 + 0.75*h2b0 + 0.25*h3b0);
      bed[t] = h6*(3.0*b0d[t] + hb0 + 0.25*h2b0);
      Vv[0][t]=ald[t]; Vv[1][t]=bed[t]; Vv[2][t]=cd[t];
      // r=0 K contributions (CH=8): col8 += al, col9 += be, col0 += c
      Kd[96+t] += ald[t]; Kd[108+t] += bed[t]; Kd[t] += cd[t];
    }
    if (t < 144) {
      int i=t/12, j=t%12;
      Md[t] = (i==j ? 1.0 : 0.0) + H1[t] + 0.5*H2[t] + H3[t]/6.0 + H4[t]/24.0;
    }
    __syncthreads();
    if (t < 144) { ws[OFF_M+t] = (float)Md[t]; Qa[t] = Md[t]; }
    if (t < 12) {
      ws[OFF_C+t]=(float)cd[t]; ws[OFF_AL+t]=(float)ald[t]; ws[OFF_BE+t]=(float)bed[t];
    }
    __syncthreads();
    // chain r=1..15: src=M^(2^(r-1)) -> dst=M^(2^r). K rounds r=1..7
    // on threads 144..179: Vv=M^r*{al,be,c}; Kd cols (8-r),(9-r),0.
    double* src = Qa; double* dst = Qb;
    for (int r = 1; r <= 15; ++r) {
      double acc = 0.0, ks = 0.0;
      if (t < 144) {
        int i=t/12, j=t%12;
#pragma unroll
        for (int m = 0; m < 12; ++m) acc += src[i*12+m]*src[m*12+j];
      }
      int w=0, i2=0;
      if (r <= 7 && t >= 144 && t < 180) {
        w=(t-144)/12; i2=(t-144)%12;
#pragma unroll
        for (int m = 0; m < 12; ++m) ks += Md[i2*12+m]*Vv[w][m];
      }
      __syncthreads();
      if (t < 144) {
        dst[t] = acc;
        if (r >= 3 && r <= 8) ws[OFF_P2+(r-3)*144+t] = (float)acc;  // M^8..M^256
        if (r == 9)  { ws[OFF_P2+6*144+t] = (float)acc; C512s[t]=acc; }
        if (r == 10) { ws[OFF_P2+7*144+t] = (float)acc; C1024s[t]=acc; }
        if (r == 11) { ws[OFF_PL+t]       = (float)acc; C2048s[t]=acc; }
        if (r == 12) { ws[OFF_PL+144+t]   = (float)acc; C4096s[t]=acc; }
        if (r == 13) { ws[OFF_PD+144+t]   = (float)acc; C8192s[t]=acc; }
        if (r == 14) { ws[OFF_PD+2*144+t] = (float)acc; C16384s[t]=acc; }
        if (r == 15) { ws[OFF_PD+4*144+t] = (float)acc; C32768s[t]=acc; }
        if (r == 8)  ws[OFF_PD+t] = (t % 13 == 0) ? 1.f : 0.f;      // Pd[0]=I
      }
      if (r <= 7 && t >= 144 && t < 180) {
        Vv[w][i2] = ks;
        if (w == 0) Kd[(8-r)*12+i2] += ks;
        else if (w == 1) Kd[(9-r)*12+i2] += ks;
        else Kd[i2] += ks;
      }
      __syncthreads();
      double* tmp = src; src = dst; dst = tmp;    // src = M^(2^r)
      if (r == 7) {                               // STAGE 1a: fold+levels0..4
        if (t < 120) ws[OFF_K+t] = (float)Kd[t];
        __syncthreads();
        if (t == 0)
          __hip_atomic_store(&sflag[0], MAGICA, __ATOMIC_RELEASE,
                             __HIP_MEMORY_SCOPE_AGENT);
      }
      if (r == 10 && t == 0)                      // STAGE 1b: level5+tree
        __hip_atomic_store(&sflag[1], MAGICB, __ATOMIC_RELEASE,
                           __HIP_MEMORY_SCOPE_AGENT);
    }
    // product round A: M^1536=C512*C1024 ; M^6144=C2048*C4096 ;
    //                  Pd3=C8192*C16384
    for (int idx = t; idx < 432; idx += BLK) {
      int w=idx/144, e=idx%144, i=e/12, j=e%12;
      const double* Ap = (w==0) ? C512s  : ((w==1) ? C2048s : C8192s);
      const double* Bp = (w==0) ? C1024s : ((w==1) ? C4096s : C16384s);
      double s = 0.0;
#pragma unroll
      for (int m = 0; m < 12; ++m) s += Ap[i*12+m]*Bp[m*12+j];
      if (w==0) ws[OFF_PA+e] = (float)s;
      else if (w==1) ws[OFF_PL+2*144+e] = (float)s;
      else { ws[OFF_PD+3*144+e] = (float)s; Pd3s[e] = s; }
    }
    __syncthreads();
    // product round B: Pd5=Pd1*Pd4 ; Pd6=Pd2*Pd4 ; Pd7=Pd3*Pd4
    for (int idx = t; idx < 432; idx += BLK) {
      int w=idx/144, e=idx%144, i=e/12, j=e%12;
      const double* Ap = (w==0) ? C8192s : ((w==1) ? C16384s : Pd3s);
      double s = 0.0;
#pragma unroll
      for (int m = 0; m < 12; ++m) s += Ap[i*12+m]*C32768s[m*12+j];
      ws[OFF_PD+(5+w)*144+e] = (float)s;
    }
    __syncthreads();
    if (t == 0)                                   // STAGE C: lookback-ready
      __hip_atomic_store(&sflag[2], MAGICC, __ATOMIC_RELEASE,
                         __HIP_MEMORY_SCOPE_AGENT);
    return;
  }

  // ================= WORKER BLOCKS =================
  int b = blockIdx.x - 1;
  int g = b*BLK + k, base = g*CH;
  bool active = (g < NCHUNK), fullc = (g <= LASTFULL);
  float to_[9];
#pragma unroll
  for (int i = 0; i < 9; ++i) to_[i] = 0.f;
  if (active) {                      // To loads overlap setup
    const float4* tp = reinterpret_cast<const float4*>(To + base);
    float4 ta = tp[0], tb = tp[1];
    to_[0]=ta.x; to_[1]=ta.y; to_[2]=ta.z; to_[3]=ta.w;
    to_[4]=tb.x; to_[5]=tb.y; to_[6]=tb.z; to_[7]=tb.w;
    to_[8] = fullc ? To[base+8] : 0.f;
  }
  // stage-1a spin (relaxed polls + one acquire)
  if (k == 0) {
    while (__hip_atomic_load(&sflag[0], __ATOMIC_RELAXED,
                             __HIP_MEMORY_SCOPE_AGENT) != MAGICA)
      __builtin_amdgcn_s_sleep(8);
    (void)__hip_atomic_load(&sflag[0], __ATOMIC_ACQUIRE,
                            __HIP_MEMORY_SCOPE_AGENT);
  }
  __syncthreads();
  {                                  // mirror stage-1a: cons[0..1040)
    const float4* s4 = reinterpret_cast<const float4*>(ws);
    float4* d4 = reinterpret_cast<float4*>(Lc);
#pragma unroll
    for (int r = 0; r < 2; ++r) {
      int idx = k + r*BLK;
      if (idx < NS1AQ) d4[idx] = s4[idx];
    }
  }
  __syncthreads();
  const float* lc = Lc;
  float v[12];
  if (fullc) fold_chunk(lc, to_, v);
  else {
#pragma unroll
    for (int i = 0; i < 12; ++i) v[i] = 0.f;
  }
  if (g == 0) {                      // fold x0 into chunk 0: v += M^8 x0
    float xi[12];
#pragma unroll
    for (int i = 0; i < 12; ++i) xi[i] = x0[i];
    mv_acc(lc + OFF_P2, xi, v);
  }
  int j = k & 63, w = k >> 6;
#pragma unroll
  for (int l = 0; l < 5; ++l) {      // in-wave scan, levels 0..4
    int off = 1 << l;
    float nb[12];
#pragma unroll
    for (int i = 0; i < 12; ++i) nb[i] = __shfl_up(v[i], (unsigned)off, 64);
    if (j >= off) mv_acc(lc + OFF_P2 + l*144, nb, v);
  }
  // stage-1b: P2[5..7] for level 5 + tree
  if (k == 0) {
    while (__hip_atomic_load(&sflag[1], __ATOMIC_RELAXED,
                             __HIP_MEMORY_SCOPE_AGENT) != MAGICB)
      __builtin_amdgcn_s_sleep(2);
    (void)__hip_atomic_load(&sflag[1], __ATOMIC_ACQUIRE,
                            __HIP_MEMORY_SCOPE_AGENT);
  }
  __syncthreads();
  {                                  // mirror stage-1b: cons[1040..1472)
    const float4* s4 = reinterpret_cast<const float4*>(ws);
    float4* d4 = reinterpret_cast<float4*>(Lc);
    if (k < NS1BQ) d4[NS1AQ + k] = s4[NS1AQ + k];
  }
  __syncthreads();
  {                                  // scan level 5
    float nb[12];
#pragma unroll
    for (int i = 0; i < 12; ++i) nb[i] = __shfl_up(v[i], 32u, 64);
    if (j >= 32) mv_acc(lc + OFF_P2 + 5*144, nb, v);
  }
  float se[12];                      // exclusive in-wave scan
#pragma unroll
  for (int i = 0; i < 12; ++i) {
    float u = __shfl_up(v[i], 1u, 64);
    se[i] = (j == 0) ? 0.f : u;
  }
  if (j == 63) {
#pragma unroll
    for (int i = 0; i < 12; ++i) Tw[w*12 + i] = v[i];
  }
  __syncthreads();
  if (k < 24) {                      // (T0,T1),(T2,T3): M^512*left + right
    int p = k/12, comp = k - p*12;
    Ta[k] = rowdot(lc + OFF_P2 + 6*144 + comp*12, Tw + 2*p*12)
          + Tw[(2*p+1)*12 + comp];
  }
  __syncthreads();
  if (k < 12) {                      // agg[b] = M^1024*Ta0 + Ta1 (agent)
    float val = rowdot(lc + OFF_P2 + 7*144 + k*12, Ta) + Ta[12 + k];
    __hip_atomic_store(&agg[b*12 + k], val, __ATOMIC_RELAXED,
                       __HIP_MEMORY_SCOPE_AGENT);
  }
  __syncthreads();
  if (k == 0)                        // publish: release flag
    __hip_atomic_store(&flags[b], 1, __ATOMIC_RELEASE,
                       __HIP_MEMORY_SCOPE_AGENT);
  // pred spins (k<32) CONCURRENT with stage-C spin (k==32)
  if (k < 32) {
    int src = b - 1 - k;
    if (src >= 0) {
      while (__hip_atomic_load(&flags[src], __ATOMIC_ACQUIRE,
                               __HIP_MEMORY_SCOPE_AGENT) == 0) {
        __builtin_amdgcn_s_sleep(1);
      }
    }
  } else if (k == 32) {
    while (__hip_atomic_load(&sflag[2], __ATOMIC_RELAXED,
                             __HIP_MEMORY_SCOPE_AGENT) != MAGICC)
      __builtin_amdgcn_s_sleep(2);
    (void)__hip_atomic_load(&sflag[2], __ATOMIC_ACQUIRE,
                            __HIP_MEMORY_SCOPE_AGENT);
  }
  __syncthreads();
  // lookback stage 1: slot=4i+jj: lkb[slot] = M^(2048*jj)*agg[b-1-slot];
  // PL read from GLOBAL ws (L2-resident, few reads)
#pragma unroll
  for (int r = 0; r < 2; ++r) {
    int idx = k + r*BLK;             // covers 384 = 32*12
    if (idx < 384) {
      int slot = idx / 12, comp = idx - slot*12;
      int src = b - 1 - slot;
      float acc = 0.f;
      if (src >= 0) {
        int jj = slot & 3;
        const float* ag = agg + src*12;
        acc = (jj == 0) ? ag[comp]
            : rowdot(ws + OFF_PL + (jj-1)*144 + comp*12, ag);
      }
      lkb[idx] = acc;
    }
  }
  __syncthreads();
  // yv[i] = sum_jj lkb[4i+jj]  (k<96)  |  Pw: P0=0, P1=T0  (k in [192,216))
  if (k < 96) {
    int i = k/12, comp = k - i*12;
    yv[k] = lkb[(4*i)*12+comp] + lkb[(4*i+1)*12+comp]
          + lkb[(4*i+2)*12+comp] + lkb[(4*i+3)*12+comp];
  } else if (k >= 192 && k < 216) {
    int q = k - 192;                 // 0..23
    if (q < 12) Pw[q] = 0.f;         // P0
    else Pw[q] = Tw[q-12];           // P1 = T0
  }
  __syncthreads();
  // zv[i] = M^(8192i)*yv[i] (k<96, PD global) | P2 = M^512*P1 + T1
  if (k < 96) {
    int i = k/12, comp = k - i*12;
    zv[k] = (i == 0) ? yv[comp]
          : rowdot(ws + OFF_PD + i*144 + comp*12, yv + i*12);
  } else if (k >= 192 && k < 204) {
    int comp = k - 192;
    Pw[24+comp] = rowdot(lc + OFF_P2 + 6*144 + comp*12, Pw+12) + Tw[12+comp];
  }
  __syncthreads();
  // Xs = sum_i zv[i] (k<12) | P3 = M^512*P2 + T2 (k in [192,204))
  if (k < 12) {
    float s = 0.f;
#pragma unroll
    for (int i = 0; i < 8; ++i) s += zv[i*12 + k];
    Xs[k] = s;
  } else if (k >= 192 && k < 204) {
    int comp = k - 192;
    Pw[36+comp] = rowdot(lc + OFF_P2 + 6*144 + comp*12, Pw+24) + Tw[24+comp];
  }
  __syncthreads();
  // Qw[w] = M^(512w)*Xs + Pw[w]  (w=0..3; I, M^512, M^1024, M^1536(global))
  if (k < 48) {
    int ww = k/12, comp = k - ww*12;
    float acc;
    if (ww == 0) acc = Xs[comp];
    else if (ww == 1) acc = rowdot(lc + OFF_P2 + 6*144 + comp*12, Xs);
    else if (ww == 2) acc = rowdot(lc + OFF_P2 + 7*144 + comp*12, Xs);
    else acc = rowdot(ws + OFF_PA + comp*12, Xs);
    Qw[k] = acc + Pw[k];
  }
  __syncthreads();
  if (!active) return;               // all barriers done
  // per-thread: x = M^(8j)*Qw[w] + se   (bits of j, P2[0..5])
  float x[12];
#pragma unroll
  for (int i = 0; i < 12; ++i) x[i] = Qw[w*12 + i];
#pragma unroll
  for (int l = 0; l < 6; ++l) {
    if ((j >> l) & 1) {
      float vn[12];
#pragma unroll
      for (int i = 0; i < 12; ++i) vn[i] = 0.f;
      mv_acc(lc + OFF_P2 + l*144, x, vn);
#pragma unroll
      for (int i = 0; i < 12; ++i) x[i] = vn[i];
    }
  }
#pragma unroll
  for (int i = 0; i < 12; ++i) x[i] += se[i];
  if (b == 0 && k == 0) {
#pragma unroll
    for (int i = 0; i < 12; ++i) x[i] += x0[i];      // start state = x0
#pragma unroll
    for (int i = 0; i < 12; ++i) out[i] = x0[i];     // row 0
  }
  // expand: 8 unconditional steps, predicated stores (NO break).
  // M hoisted into 36 NAMED float4 locals (no array -> registers).
  float cv[12], av[12], bv[12];
#pragma unroll
  for (int i = 0; i < 12; ++i) {
    cv[i] = lc[OFF_C + i]; av[i] = lc[OFF_AL + i]; bv[i] = lc[OFF_BE + i];
  }
  const float4* Mq = reinterpret_cast<const float4*>(lc + OFF_M);
  float4 m0 =Mq[0],  m1 =Mq[1],  m2 =Mq[2],  m3 =Mq[3],  m4 =Mq[4],  m5 =Mq[5];
  float4 m6 =Mq[6],  m7 =Mq[7],  m8 =Mq[8],  m9 =Mq[9],  m10=Mq[10], m11=Mq[11];
  float4 m12=Mq[12], m13=Mq[13], m14=Mq[14], m15=Mq[15], m16=Mq[16], m17=Mq[17];
  float4 m18=Mq[18], m19=Mq[19], m20=Mq[20], m21=Mq[21], m22=Mq[22], m23=Mq[23];
  float4 m24=Mq[24], m25=Mq[25], m26=Mq[26], m27=Mq[27], m28=Mq[28], m29=Mq[29];
  float4 m30=Mq[30], m31=Mq[31], m32=Mq[32], m33=Mq[33], m34=Mq[34], m35=Mq[35];
#define EROW(i, A, B, Cq) \
  xn[i] = FMA4(Cq, x[8],x[9],x[10],x[11], \
           FMA4(B, x[4],x[5],x[6],x[7], \
            FMA4(A, x[0],x[1],x[2],x[3], \
             fmaf(bv[i],ton,fmaf(av[i],tot,cv[i])))))
#pragma unroll
  for (int s = 0; s < CH; ++s) {
    float tot = to_[s], ton = to_[s+1];
    float xn[12];
    EROW(0,  m0,  m1,  m2);  EROW(1,  m3,  m4,  m5);
    EROW(2,  m6,  m7,  m8);  EROW(3,  m9,  m10, m11);
    EROW(4,  m12, m13, m14); EROW(5,  m15, m16, m17);
    EROW(6,  m18, m19, m20); EROW(7,  m21, m22, m23);
    EROW(8,  m24, m25, m26); EROW(9,  m27, m28, m29);
    EROW(10, m30, m31, m32); EROW(11, m33, m34, m35);
    int tt = base + s;
    if (tt < S_STEPS) {
      float4* op = reinterpret_cast<float4*>(out + (size_t)(tt+1)*12);
      op[0] = make_float4(xn[0],xn[1],xn[2],xn[3]);
      op[1] = make_float4(xn[4],xn[5],xn[6],xn[7]);
      op[2] = make_float4(xn[8],xn[9],xn[10],xn[11]);
    }
#pragma unroll
    for (int i = 0; i < 12; ++i) x[i] = xn[i];
  }
#undef EROW
}

extern "C" void kernel_launch(void* const* d_in, const int* in_sizes, int n_in,
                              void* d_out, int out_size, void* d_ws, size_t ws_size,
                              hipStream_t stream) {
  const float* t_eval    = (const float*)d_in[0];
  const float* x0        = (const float*)d_in[1];
  const float* A         = (const float*)d_in[2];
  const float* B         = (const float*)d_in[3];
  const float* To        = (const float*)d_in[4];
  const float* loads_raw = (const float*)d_in[5];
  const float* areas     = (const float*)d_in[6];
  float* out = (float*)d_out;
  float* ws  = (float*)d_ws;

  fused_all<<<NB_W + 1, BLK, 0, stream>>>(t_eval, A, B, loads_raw, areas,
                                          ws, To, x0, out);
}